// Round 2
// baseline (362.776 us; speedup 1.0000x reference)
//
#include <hip/hip_runtime.h>
#include <cstddef>

// Problem constants: N=64 state dim, L=16384 seq, BATCH=512, chunk m=128.
static constexpr int RCN = 512 * 128;   // 65536 (row, chunk) pairs

// ws layout (float offsets)
static constexpr size_t WS_W  = 0;       // W[r][i] = (Ab^r Bb)_i, 128x64 fp32
static constexpr size_t WS_G  = 8192;    // fused weights G, 192x128 fp32
static constexpr size_t WS_MD = 32768;   // M = Ab^128, 64x64 DOUBLE (8192 floats)
static constexpr size_t WS_BV = 40960;   // chunk vectors b, RCN x 64 fp32
static constexpr size_t WS_X  = WS_BV + (size_t)RCN * 64;  // chunk states X, RCN x 64 fp32

// ---------------------------------------------------------------------------
// In-place 64x64x64 fp64 matmul in LDS, 2x2 register tile per thread,
// 1024 threads (16 waves = 4 waves/SIMD for latency hiding — the measured
// bottleneck was 1 wave/SIMD latency exposure, VALUBusy ~26%/CU).
//   A reads: half-wave-uniform rows -> broadcast (free).
//   B reads: contiguous pairs across lanes -> bandwidth-minimal.
// ---------------------------------------------------------------------------
template<bool ADD>
__device__ __forceinline__ void mm64x2(const double* A, const double* B, double* D,
                                       int tr2, int tc2)
{
  double a00 = 0, a01 = 0, a10 = 0, a11 = 0;
#pragma unroll 8
  for (int c = 0; c < 64; ++c) {
    double av0 = A[(tr2 + 0) * 65 + c];
    double av1 = A[(tr2 + 1) * 65 + c];
    double bv0 = B[c * 65 + tc2 + 0];
    double bv1 = B[c * 65 + tc2 + 1];
    a00 = fma(av0, bv0, a00); a01 = fma(av0, bv1, a01);
    a10 = fma(av1, bv0, a10); a11 = fma(av1, bv1, a11);
  }
  double o00, o01, o10, o11;
  if (ADD) {
    o00 = D[(tr2 + 0) * 65 + tc2 + 0]; o01 = D[(tr2 + 0) * 65 + tc2 + 1];
    o10 = D[(tr2 + 1) * 65 + tc2 + 0]; o11 = D[(tr2 + 1) * 65 + tc2 + 1];
  }
  __syncthreads();   // all reads of A/B/D complete before overwrite
  D[(tr2 + 0) * 65 + tc2 + 0] = ADD ? (o00 + a00) : a00;
  D[(tr2 + 0) * 65 + tc2 + 1] = ADD ? (o01 + a01) : a01;
  D[(tr2 + 1) * 65 + tc2 + 0] = ADD ? (o10 + a10) : a10;
  D[(tr2 + 1) * 65 + tc2 + 1] = ADD ? (o11 + a11) : a11;
  __syncthreads();
}

// ---------------------------------------------------------------------------
// Kernel A: discretize + build all weights. 1 block x 1024 threads.
//   Numerics identical (fp64 Neumann inverse, fp64 squaring chain, fp32 W/H
//   storage with fp64 accumulate). 16 waves = 4/SIMD hides LDS latency.
// ---------------------------------------------------------------------------
__global__ __launch_bounds__(1024) void k_precomp(
    const float* __restrict__ Ain, const float* __restrict__ Bin,
    const float* __restrict__ Cin, const float* __restrict__ Din,
    const float* __restrict__ LS, float* ws)
{
  __shared__ double Xd[64 * 65];   // hA, then hA^(2^k)
  __shared__ double Pd[64 * 65];   // Z -> N1 -> Ab -> P-chain -> M
  __shared__ float  Wf[128 * 65];  // W[r][i], stride 65
  __shared__ float  Hf[128 * 65];  // H[r][i] = (C Ab^{r+1})_i
  __shared__ float  Kf[128];

  const int t   = threadIdx.x;            // 0..1023
  const int tr2 = (t >> 5) << 1;          // row base of 2x2 tile (0..62)
  const int tc2 = (t & 31) << 1;          // col base of 2x2 tile (0..62)

  float*  Wg  = ws + WS_W;
  float*  Gg  = ws + WS_G;
  double* Mgd = (double*)(ws + WS_MD);

  const double step = exp((double)LS[0]);
  const double h = 0.5 * step;

  // X = h*A ; Z = I + X
  for (int idx = t; idx < 4096; idx += 1024) {
    int i = idx >> 6, j = idx & 63;
    double a = h * (double)Ain[idx];
    Xd[i * 65 + j] = a;
    Pd[i * 65 + j] = a + ((i == j) ? 1.0 : 0.0);
  }
  __syncthreads();

  // Product-form Neumann: Z <- Z*(I + X^{2^k}), X <- X^2, k = 1..3
  // => Z = sum_{j=0}^{15} X^j ; truncation ||X||^16 <= 0.1^16 = 1e-16.
  for (int k = 0; k < 3; ++k) {
    mm64x2<false>(Xd, Xd, Xd, tr2, tc2);   // X <- X*X
    mm64x2<true >(Pd, Xd, Pd, tr2, tc2);   // Z <- Z + Z*X
  }

  // Pd = N1. Bb = step * N1 @ B  -> W[0]
  if (t < 64) {
    double bb = 0.0;
    for (int c = 0; c < 64; ++c) bb = fma(Pd[t * 65 + c], (double)Bin[c], bb);
    Wf[t] = (float)(bb * step);   // W row 0
  }
  __syncthreads();  // all N1 reads complete before overwrite

  // Ab = 2*N1 - I (in place)
  for (int idx = t; idx < 4096; idx += 1024) {
    int i = idx >> 6, j = idx & 63;
    Pd[i * 65 + j] = 2.0 * Pd[i * 65 + j] - ((i == j) ? 1.0 : 0.0);
  }
  __syncthreads();

  // H[0] = C @ Ab
  if (t < 64) {
    double hh = 0.0;
    for (int c = 0; c < 64; ++c) hh = fma((double)Cin[c], Pd[c * 65 + t], hh);
    Hf[t] = (float)hh;
  }
  __syncthreads();

  // Log-doubling: entry invariant P = Ab^n (n = 2^k), W[0..n), H[0..n) valid.
  //   W[n+r][i] = sum_c W[r][c] * P[i][c]   (row-row)
  //   H[n+r][i] = sum_c H[r][c] * P[c][i]   (row-col)
  //   P <- P*P  (shared with the M = Ab^128 chain)
  // Stage writes (rows >= n) are disjoint from all stage reads (rows < n,
  // Pd); mm64x2's internal barriers provide all needed ordering.
  for (int k = 0; k < 7; ++k) {
    const int n = 1 << k;
    if (n <= 16) {
      // n*64 <= 1024 items; each active thread computes one W and one H out.
      if (t < (n << 6)) {
        int r = t >> 6, ii = t & 63;        // r wave-uniform, ii per-lane
        double aw = 0.0, ah = 0.0;
#pragma unroll 4
        for (int c = 0; c < 64; ++c) {
          aw = fma(Pd[ii * 65 + c], (double)Wf[r * 65 + c], aw);
          ah = fma((double)Hf[r * 65 + c], Pd[c * 65 + ii], ah);
        }
        Wf[(n + r) * 65 + ii] = (float)aw;
        Hf[(n + r) * 65 + ii] = (float)ah;
      }
    } else if (n == 32) {
      // thread -> (r = t>>5 in [0,32), i pair). W and H fused per thread.
      const int r  = t >> 5;
      const int i2 = (t & 31) << 1;
      double w0 = 0, w1 = 0, h0 = 0, h1 = 0;
#pragma unroll 4
      for (int c = 0; c < 64; ++c) {
        double wr = (double)Wf[r * 65 + c];
        w0 = fma(wr, Pd[(i2 + 0) * 65 + c], w0);
        w1 = fma(wr, Pd[(i2 + 1) * 65 + c], w1);
        double hr = (double)Hf[r * 65 + c];
        h0 = fma(hr, Pd[c * 65 + i2 + 0], h0);
        h1 = fma(hr, Pd[c * 65 + i2 + 1], h1);
      }
      Wf[(32 + r) * 65 + i2 + 0] = (float)w0;
      Wf[(32 + r) * 65 + i2 + 1] = (float)w1;
      Hf[(32 + r) * 65 + i2 + 0] = (float)h0;
      Hf[(32 + r) * 65 + i2 + 1] = (float)h1;
    } else {  // n == 64: 2x2 tiles for W and H, fused per thread
      const int r2 = tr2, i2 = tc2;
      double w00 = 0, w01 = 0, w10 = 0, w11 = 0;
      double h00 = 0, h01 = 0, h10 = 0, h11 = 0;
#pragma unroll 4
      for (int c = 0; c < 64; ++c) {
        double wa = (double)Wf[(r2 + 0) * 65 + c];
        double wb = (double)Wf[(r2 + 1) * 65 + c];
        double p0 = Pd[(i2 + 0) * 65 + c];
        double p1 = Pd[(i2 + 1) * 65 + c];
        w00 = fma(wa, p0, w00); w01 = fma(wa, p1, w01);
        w10 = fma(wb, p0, w10); w11 = fma(wb, p1, w11);
        double ha = (double)Hf[(r2 + 0) * 65 + c];
        double hb = (double)Hf[(r2 + 1) * 65 + c];
        double q0 = Pd[c * 65 + i2 + 0];
        double q1 = Pd[c * 65 + i2 + 1];
        h00 = fma(ha, q0, h00); h01 = fma(ha, q1, h01);
        h10 = fma(hb, q0, h10); h11 = fma(hb, q1, h11);
      }
      Wf[(64 + r2 + 0) * 65 + i2 + 0] = (float)w00;
      Wf[(64 + r2 + 0) * 65 + i2 + 1] = (float)w01;
      Wf[(64 + r2 + 1) * 65 + i2 + 0] = (float)w10;
      Wf[(64 + r2 + 1) * 65 + i2 + 1] = (float)w11;
      Hf[(64 + r2 + 0) * 65 + i2 + 0] = (float)h00;
      Hf[(64 + r2 + 0) * 65 + i2 + 1] = (float)h01;
      Hf[(64 + r2 + 1) * 65 + i2 + 0] = (float)h10;
      Hf[(64 + r2 + 1) * 65 + i2 + 1] = (float)h11;
    }
    // P <- P*P (its barriers also order the W/H writes vs next-stage reads)
    mm64x2<false>(Pd, Pd, Pd, tr2, tc2);
  }

  // Pd = Ab^128 = M (fp64) -> global for k_scan
  for (int idx = t; idx < 4096; idx += 1024)
    Mgd[idx] = Pd[(idx >> 6) * 65 + (idx & 63)];

  // K[r] = C . W[r]
  if (t < 128) {
    double s = 0.0;
    for (int c = 0; c < 64; ++c) s = fma((double)Cin[c], (double)Wf[t * 65 + c], s);
    Kf[t] = (float)s;
  }
  __syncthreads();

  // W -> global (dense 64-stride for k_chunkvec)
  for (int idx = t; idx < 8192; idx += 1024)
    Wg[idx] = Wf[(idx >> 6) * 65 + (idx & 63)];

  // G Toeplitz part: G[k][r] = K[r-k] (r>=k) + D*(k==r)
  const float Dval = Din[0];
  for (int idx = t; idx < 16384; idx += 1024) {
    int k = idx >> 7, r = idx & 127;
    float v = (r >= k) ? Kf[r - k] : 0.f;
    if (k == r) v += Dval;
    Gg[idx] = v;
  }
  // G cross-chunk part: G[128+i][r] = H[r][i]
  for (int idx = t; idx < 8192; idx += 1024) {
    int i = idx >> 7, r = idx & 127;
    Gg[(128 + i) * 128 + r] = Hf[r * 65 + i];
  }
}

// ---------------------------------------------------------------------------
// Kernel B: chunk input vectors  b[rc][i] = sum_k u[rc][k] * W[127-k][i]
// GEMM M=65536, N=64, K=128. Block = 128 rc-rows, 128 threads, 8x8 tiles.
// ---------------------------------------------------------------------------
__global__ __launch_bounds__(128) void k_chunkvec(
    const float* __restrict__ u, const float* __restrict__ Wg,
    float* __restrict__ bout)
{
  __shared__ float As[32 * 132];  // [kk][rcl], transposed u slice
  __shared__ float Bs[32 * 68];   // [kk][i]
  const int t = threadIdx.x;
  const int rc0 = blockIdx.x << 7;
  const int trow = (t >> 3) << 3;
  const int tcol = (t & 7) << 3;
  float acc[8][8];
#pragma unroll
  for (int i = 0; i < 8; ++i)
#pragma unroll
    for (int j = 0; j < 8; ++j) acc[i][j] = 0.f;

  for (int sl = 0; sl < 4; ++sl) {
    for (int it = t; it < 1024; it += 128) {
      int rcl = it >> 3, k4 = (it & 7) << 2;
      float4 v = *(const float4*)&u[((size_t)(rc0 + rcl) << 7) + (sl << 5) + k4];
      As[(k4 + 0) * 132 + rcl] = v.x;
      As[(k4 + 1) * 132 + rcl] = v.y;
      As[(k4 + 2) * 132 + rcl] = v.z;
      As[(k4 + 3) * 132 + rcl] = v.w;
    }
    for (int it = t; it < 512; it += 128) {
      int kk = it >> 4, i4 = (it & 15) << 2;
      *(float4*)&Bs[kk * 68 + i4] =
          *(const float4*)&Wg[((size_t)(127 - ((sl << 5) + kk)) << 6) + i4];
    }
    __syncthreads();
#pragma unroll 4
    for (int kk = 0; kk < 32; ++kk) {
      float av[8], bv[8];
      *(float4*)&av[0] = *(const float4*)&As[kk * 132 + trow];
      *(float4*)&av[4] = *(const float4*)&As[kk * 132 + trow + 4];
      *(float4*)&bv[0] = *(const float4*)&Bs[kk * 68 + tcol];
      *(float4*)&bv[4] = *(const float4*)&Bs[kk * 68 + tcol + 4];
#pragma unroll
      for (int i = 0; i < 8; ++i)
#pragma unroll
        for (int j = 0; j < 8; ++j) acc[i][j] = fmaf(av[i], bv[j], acc[i][j]);
    }
    __syncthreads();
  }
#pragma unroll
  for (int i = 0; i < 8; ++i) {
    size_t base = ((size_t)(rc0 + trow + i) << 6) + tcol;
    *(float4*)&bout[base]     = make_float4(acc[i][0], acc[i][1], acc[i][2], acc[i][3]);
    *(float4*)&bout[base + 4] = make_float4(acc[i][4], acc[i][5], acc[i][6], acc[i][7]);
  }
}

// ---------------------------------------------------------------------------
// Kernel C: per-row chunk-state scan in fp64. X_0 = 0; X_{j+1} = M X_j + b_j.
// ---------------------------------------------------------------------------
__global__ __launch_bounds__(256) void k_scan(
    const double* __restrict__ Mg, const float* __restrict__ bv,
    float* __restrict__ Xg)
{
  __shared__ double xs[64];
  __shared__ double part[3 * 64];
  const int t = threadIdx.x;
  const int i = t & 63, q = t >> 6;   // q is wave-uniform
  double Mr[16];
#pragma unroll
  for (int c = 0; c < 16; ++c) Mr[c] = Mg[((size_t)i << 6) + (q << 4) + c];
  const float* br = bv + ((size_t)blockIdx.x << 13);
  float* Xr = Xg + ((size_t)blockIdx.x << 13);
  if (t < 64) xs[t] = 0.0;
  __syncthreads();
  for (int j = 0; j < 128; ++j) {
    double s0 = 0, s1 = 0, s2 = 0, s3 = 0;
#pragma unroll
    for (int c = 0; c < 16; c += 4) {   // xs reads are wave-uniform broadcasts
      s0 = fma(Mr[c + 0], xs[(q << 4) + c + 0], s0);
      s1 = fma(Mr[c + 1], xs[(q << 4) + c + 1], s1);
      s2 = fma(Mr[c + 2], xs[(q << 4) + c + 2], s2);
      s3 = fma(Mr[c + 3], xs[(q << 4) + c + 3], s3);
    }
    double ps = (s0 + s1) + (s2 + s3);
    if (q) part[((q - 1) << 6) + i] = ps;
    __syncthreads();
    if (q == 0) {
      double xold = xs[i];
      Xr[(j << 6) + i] = (float)xold;                 // state at chunk start
      xs[i] = (double)br[(j << 6) + i] + ps + part[i] + part[64 + i] + part[128 + i];
    }
    __syncthreads();
  }
}

// ---------------------------------------------------------------------------
// Kernel D: main output GEMM. y[rc][r] = sum_{k<128} u[rc][k] G[k][r]
//                                       + sum_i X[rc][i] G[128+i][r]
// ---------------------------------------------------------------------------
__global__ __launch_bounds__(256) void k_main(
    const float* __restrict__ u, const float* __restrict__ Xg,
    const float* __restrict__ Gg, float* __restrict__ out)
{
  __shared__ float As[32 * 132];  // [kk][rcl]
  __shared__ float Bs[32 * 132];  // [kk][r]
  const int t = threadIdx.x;
  const int rc0 = blockIdx.x << 7;
  const int trow = (t >> 4) << 3;
  const int tcol = (t & 15) << 3;
  float acc[8][8];
#pragma unroll
  for (int i = 0; i < 8; ++i)
#pragma unroll
    for (int j = 0; j < 8; ++j) acc[i][j] = 0.f;

  for (int sl = 0; sl < 6; ++sl) {
    const int k0 = sl << 5;
    for (int it = t; it < 1024; it += 256) {
      int rcl = it >> 3, k4 = (it & 7) << 2;
      int kg = k0 + k4;
      float4 v;
      if (kg < 128)
        v = *(const float4*)&u[((size_t)(rc0 + rcl) << 7) + kg];
      else
        v = *(const float4*)&Xg[((size_t)(rc0 + rcl) << 6) + (kg - 128)];
      As[(k4 + 0) * 132 + rcl] = v.x;
      As[(k4 + 1) * 132 + rcl] = v.y;
      As[(k4 + 2) * 132 + rcl] = v.z;
      As[(k4 + 3) * 132 + rcl] = v.w;
    }
    for (int it = t; it < 1024; it += 256) {
      int kk = it >> 5, r4 = (it & 31) << 2;
      *(float4*)&Bs[kk * 132 + r4] = *(const float4*)&Gg[(size_t)(k0 + kk) * 128 + r4];
    }
    __syncthreads();
#pragma unroll 4
    for (int kk = 0; kk < 32; ++kk) {
      float av[8], bv[8];
      *(float4*)&av[0] = *(const float4*)&As[kk * 132 + trow];
      *(float4*)&av[4] = *(const float4*)&As[kk * 132 + trow + 4];
      *(float4*)&bv[0] = *(const float4*)&Bs[kk * 132 + tcol];
      *(float4*)&bv[4] = *(const float4*)&Bs[kk * 132 + tcol + 4];
#pragma unroll
      for (int i = 0; i < 8; ++i)
#pragma unroll
        for (int j = 0; j < 8; ++j) acc[i][j] = fmaf(av[i], bv[j], acc[i][j]);
    }
    __syncthreads();
  }
#pragma unroll
  for (int i = 0; i < 8; ++i) {
    size_t base = ((size_t)(rc0 + trow + i) << 7) + tcol;
    *(float4*)&out[base]     = make_float4(acc[i][0], acc[i][1], acc[i][2], acc[i][3]);
    *(float4*)&out[base + 4] = make_float4(acc[i][4], acc[i][5], acc[i][6], acc[i][7]);
  }
}

// ---------------------------------------------------------------------------
extern "C" void kernel_launch(void* const* d_in, const int* in_sizes, int n_in,
                              void* d_out, int out_size, void* d_ws, size_t ws_size,
                              hipStream_t stream) {
  (void)in_sizes; (void)n_in; (void)out_size; (void)ws_size;
  const float* u  = (const float*)d_in[0];
  const float* A  = (const float*)d_in[1];
  const float* Bv = (const float*)d_in[2];
  const float* Cv = (const float*)d_in[3];
  const float* Dv = (const float*)d_in[4];
  const float* ls = (const float*)d_in[5];
  float* out = (float*)d_out;
  float* ws  = (float*)d_ws;

  k_precomp<<<1, 1024, 0, stream>>>(A, Bv, Cv, Dv, ls, ws);
  k_chunkvec<<<512, 128, 0, stream>>>(u, ws + WS_W, ws + WS_BV);
  k_scan<<<512, 256, 0, stream>>>((const double*)(ws + WS_MD), ws + WS_BV, ws + WS_X);
  k_main<<<512, 256, 0, stream>>>(u, ws + WS_X, ws + WS_G, out);
}

// Round 4
// 274.994 us; speedup vs baseline: 1.3192x; 1.3192x over previous
//
#include <hip/hip_runtime.h>
#include <cstddef>

typedef double f64x4 __attribute__((ext_vector_type(4)));

// Problem constants: N=64 state dim, L=16384 seq, BATCH=512, chunk m=128.
static constexpr int RCN = 512 * 128;   // 65536 (row, chunk) pairs

// ws layout (float offsets)
static constexpr size_t WS_W  = 0;       // W[r][i] = (Ab^r Bb)_i, 128x64 fp32
static constexpr size_t WS_G  = 8192;    // fused weights G, 192x128 fp32
static constexpr size_t WS_MD = 32768;   // M = Ab^128, 64x64 DOUBLE (8192 floats)
static constexpr size_t WS_BV = 40960;   // chunk vectors b, RCN x 64 fp32
static constexpr size_t WS_X  = WS_BV + (size_t)RCN * 64;  // chunk states X, RCN x 64 fp32

// ---------------------------------------------------------------------------
// f64 MFMA layout probe. The 16x16x4 f64 instruction's lane->element maps
// were NOT among the gfx950-verified cells; probe them at runtime and verify
// the full instruction semantics exactly. Pure-register, no barriers: every
// wave computes the identical block-uniform answer.
// Assumed A map: A[i][k] at lane i+16k; B map: B[k][j] at lane j+16k.
// C/D map: discovered (rowm[r], colm). Verification catches ANY wrong
// assumption -> exact-equality fail -> VALU fallback.
// ---------------------------------------------------------------------------
__device__ __forceinline__ double probeE(int i, int k) {
  return (double)(((i * 3 + k * 5) & 7) - 3);
}
__device__ __forceinline__ double probeF(int k, int j) {
  return (double)(((k * 7 + j * 2) & 7) - 4);
}

__device__ __forceinline__ bool probe_mfma_layout(int lr, int lq, int rowm[4], int* colm_out)
{
  f64x4 z; z[0] = 0.0; z[1] = 0.0; z[2] = 0.0; z[3] = 0.0;
  // probe 1: A[i][k] = i, B = 1  => D[i][j] = 4i: acc[r] reveals owned row.
  f64x4 p1 = __builtin_amdgcn_mfma_f64_16x16x4f64((double)lr, 1.0, z, 0, 0, 0);
  // probe 2: A = 1, B[k][j] = j  => D[i][j] = 4j: reveals owned column.
  f64x4 p2 = __builtin_amdgcn_mfma_f64_16x16x4f64(1.0, (double)lr, z, 0, 0, 0);
  bool okl = true;
#pragma unroll
  for (int r = 0; r < 4; ++r) {
    int rr = (int)(p1[r] * 0.25 + 0.5);
    okl = okl && (p1[r] == 4.0 * (double)rr) && rr >= 0 && rr < 16;
    rowm[r] = rr & 15;
    okl = okl && (p2[r] == p2[0]);          // column must be reg-independent
  }
  int cc = (int)(p2[0] * 0.25 + 0.5);
  okl = okl && (p2[0] == 4.0 * (double)cc) && cc >= 0 && cc < 16;
  *colm_out = cc & 15;
  // full verify: D = E*F, distinct small-integer entries, exact in f64.
  f64x4 d = __builtin_amdgcn_mfma_f64_16x16x4f64(probeE(lr, lq), probeF(lq, lr), z, 0, 0, 0);
#pragma unroll
  for (int r = 0; r < 4; ++r) {
    double ref = 0.0;
#pragma unroll
    for (int k = 0; k < 4; ++k) ref += probeE(rowm[r], k) * probeF(k, cc & 15);
    okl = okl && (d[r] == ref);
  }
  return __all(okl) != 0;
}

// ---------------------------------------------------------------------------
// In-place 64x64x64 fp64 matmul in LDS via v_mfma_f64_16x16x4_f64 with the
// PROBED C/D mapping. 16 waves; wave (wi,wj) owns one 16x16 output tile.
// 32 ds_read_b64 per wave per matmul (~8x fewer LDS instructions than the
// VALU 2x2 path, which is the measured bottleneck at ~6 cyc/LDS-instr).
// ---------------------------------------------------------------------------
template<bool ADD>
__device__ __forceinline__ void mm64_mfma(const double* A, const double* B, double* D,
                                          int wi, int wj, int lr, int lq,
                                          const int rowm[4], int colm)
{
  f64x4 acc;
  if (ADD) {
#pragma unroll
    for (int r = 0; r < 4; ++r)
      acc[r] = D[(wi * 16 + rowm[r]) * 65 + wj * 16 + colm];
  } else {
    acc[0] = 0.0; acc[1] = 0.0; acc[2] = 0.0; acc[3] = 0.0;
  }
#pragma unroll
  for (int kb = 0; kb < 16; ++kb) {
    double a = A[(wi * 16 + lr) * 65 + kb * 4 + lq];
    double b = B[(kb * 4 + lq) * 65 + wj * 16 + lr];
    acc = __builtin_amdgcn_mfma_f64_16x16x4f64(a, b, acc, 0, 0, 0);
  }
  __syncthreads();   // all reads of A/B/D complete before overwrite
#pragma unroll
  for (int r = 0; r < 4; ++r)
    D[(wi * 16 + rowm[r]) * 65 + wj * 16 + colm] = acc[r];
  __syncthreads();
}

// One 16x16 tile of the W/H log-doubling expansion (MFMA, probed maps).
//   W[n+r][i] = sum_c W[r][c] * P[i][c]  -> D = W * P^T
//   H[n+r][i] = sum_c H[r][c] * P[c][i]  -> D = H * P
// Stale A rows >= n only feed masked-out D rows. No internal barrier.
__device__ __forceinline__ void wh_tile(const float* Wf, const float* Hf,
                                        const double* Pd, float* Wo, float* Ho,
                                        int n, bool isW, int wi, int wj,
                                        int lr, int lq, const int rowm[4], int colm)
{
  f64x4 acc;
  acc[0] = 0.0; acc[1] = 0.0; acc[2] = 0.0; acc[3] = 0.0;
#pragma unroll
  for (int kb = 0; kb < 16; ++kb) {
    double a, b;
    if (isW) {
      a = (double)Wf[(wi * 16 + lr) * 65 + kb * 4 + lq];
      b = Pd[(wj * 16 + lr) * 65 + kb * 4 + lq];     // P^T fragment
    } else {
      a = (double)Hf[(wi * 16 + lr) * 65 + kb * 4 + lq];
      b = Pd[(kb * 4 + lq) * 65 + wj * 16 + lr];     // P fragment
    }
    acc = __builtin_amdgcn_mfma_f64_16x16x4f64(a, b, acc, 0, 0, 0);
  }
#pragma unroll
  for (int r = 0; r < 4; ++r) {
    int drow = wi * 16 + rowm[r];
    if (drow < n) {
      if (isW) Wo[(n + drow) * 65 + wj * 16 + colm] = (float)acc[r];
      else     Ho[(n + drow) * 65 + wj * 16 + colm] = (float)acc[r];
    }
  }
}

// ---------------------------------------------------------------------------
// VALU fallback matmul (verbatim from the round-2 known-passing kernel).
// ---------------------------------------------------------------------------
template<bool ADD>
__device__ __forceinline__ void mm64x2(const double* A, const double* B, double* D,
                                       int tr2, int tc2)
{
  double a00 = 0, a01 = 0, a10 = 0, a11 = 0;
#pragma unroll 8
  for (int c = 0; c < 64; ++c) {
    double av0 = A[(tr2 + 0) * 65 + c];
    double av1 = A[(tr2 + 1) * 65 + c];
    double bv0 = B[c * 65 + tc2 + 0];
    double bv1 = B[c * 65 + tc2 + 1];
    a00 = fma(av0, bv0, a00); a01 = fma(av0, bv1, a01);
    a10 = fma(av1, bv0, a10); a11 = fma(av1, bv1, a11);
  }
  double o00, o01, o10, o11;
  if (ADD) {
    o00 = D[(tr2 + 0) * 65 + tc2 + 0]; o01 = D[(tr2 + 0) * 65 + tc2 + 1];
    o10 = D[(tr2 + 1) * 65 + tc2 + 0]; o11 = D[(tr2 + 1) * 65 + tc2 + 1];
  }
  __syncthreads();
  D[(tr2 + 0) * 65 + tc2 + 0] = ADD ? (o00 + a00) : a00;
  D[(tr2 + 0) * 65 + tc2 + 1] = ADD ? (o01 + a01) : a01;
  D[(tr2 + 1) * 65 + tc2 + 0] = ADD ? (o10 + a10) : a10;
  D[(tr2 + 1) * 65 + tc2 + 1] = ADD ? (o11 + a11) : a11;
  __syncthreads();
}

// ---------------------------------------------------------------------------
// Kernel A: discretize + build all weights. 1 block x 1024 threads (16 waves).
// fp64 Neumann inverse, fp64 squaring chain, fp32 W/H storage with fp64
// accumulate. Matmuls on the f64 matrix pipe when the probed layout
// verifies; exact VALU fallback otherwise.
// ---------------------------------------------------------------------------
__global__ __launch_bounds__(1024) void k_precomp(
    const float* __restrict__ Ain, const float* __restrict__ Bin,
    const float* __restrict__ Cin, const float* __restrict__ Din,
    const float* __restrict__ LS, float* ws)
{
  __shared__ double Xd[64 * 65];   // hA, then hA^(2^k)
  __shared__ double Pd[64 * 65];   // Z -> N1 -> Ab -> P-chain -> M
  __shared__ float  Wf[128 * 65];  // W[r][i], stride 65
  __shared__ float  Hf[128 * 65];  // H[r][i] = (C Ab^{r+1})_i
  __shared__ float  Kf[128];

  const int t    = threadIdx.x;        // 0..1023
  const int wave = t >> 6;             // 0..15
  const int lane = t & 63;
  const int lr   = lane & 15;
  const int lq   = lane >> 4;
  const int wv_i = wave >> 2;          // MFMA tile row
  const int wv_j = wave & 3;           // MFMA tile col
  const int tr2  = (t >> 5) << 1;      // VALU fallback 2x2 tile
  const int tc2  = (t & 31) << 1;

  int rowm[4]; int colm;
  const bool use_mfma = probe_mfma_layout(lr, lq, rowm, &colm);

  float*  Wg  = ws + WS_W;
  float*  Gg  = ws + WS_G;
  double* Mgd = (double*)(ws + WS_MD);

  const double step = exp((double)LS[0]);
  const double h = 0.5 * step;

  // X = h*A ; Z = I + X
  for (int idx = t; idx < 4096; idx += 1024) {
    int i = idx >> 6, j = idx & 63;
    double a = h * (double)Ain[idx];
    Xd[i * 65 + j] = a;
    Pd[i * 65 + j] = a + ((i == j) ? 1.0 : 0.0);
  }
  __syncthreads();

  // Product-form Neumann: Z <- Z*(I + X^{2^k}), X <- X^2, k = 1..3
  // => Z = sum_{j=0}^{15} X^j ; truncation ||X||^16 <= 0.1^16 = 1e-16.
  if (use_mfma) {
    for (int k = 0; k < 3; ++k) {
      mm64_mfma<false>(Xd, Xd, Xd, wv_i, wv_j, lr, lq, rowm, colm);
      mm64_mfma<true >(Pd, Xd, Pd, wv_i, wv_j, lr, lq, rowm, colm);
    }
  } else {
    for (int k = 0; k < 3; ++k) {
      mm64x2<false>(Xd, Xd, Xd, tr2, tc2);
      mm64x2<true >(Pd, Xd, Pd, tr2, tc2);
    }
  }

  // Pd = N1. Bb = step * N1 @ B  -> W[0]
  if (t < 64) {
    double bb = 0.0;
    for (int c = 0; c < 64; ++c) bb = fma(Pd[t * 65 + c], (double)Bin[c], bb);
    Wf[t] = (float)(bb * step);   // W row 0
  }
  __syncthreads();  // all N1 reads complete before overwrite

  // Ab = 2*N1 - I (in place)
  for (int idx = t; idx < 4096; idx += 1024) {
    int i = idx >> 6, j = idx & 63;
    Pd[i * 65 + j] = 2.0 * Pd[i * 65 + j] - ((i == j) ? 1.0 : 0.0);
  }
  __syncthreads();

  // H[0] = C @ Ab
  if (t < 64) {
    double hh = 0.0;
    for (int c = 0; c < 64; ++c) hh = fma((double)Cin[c], Pd[c * 65 + t], hh);
    Hf[t] = (float)hh;
  }
  __syncthreads();

  // Log-doubling: entry invariant P = Ab^n (n = 2^k), W[0..n), H[0..n) valid.
  //   W[n+r][i] = sum_c W[r][c] * P[i][c]
  //   H[n+r][i] = sum_c H[r][c] * P[c][i]
  //   P <- P*P  (shared with the M = Ab^128 chain)
  // Stage writes (rows >= n) are disjoint from stage reads; the matmul's
  // internal barriers provide all needed ordering.
  if (use_mfma) {
    for (int k = 0; k < 7; ++k) {
      const int n     = 1 << k;
      const int tpm   = (n + 15) >> 4;   // tile-rows needed
      const int tiles = tpm << 2;        // tiles per matmul
      if (tiles <= 8) {
        if (wave < 2 * tiles) {
          const bool isW = wave < tiles;
          const int  w   = isW ? wave : wave - tiles;
          wh_tile(Wf, Hf, Pd, Wf, Hf, n, isW, w >> 2, w & 3, lr, lq, rowm, colm);
        }
      } else {  // n == 64: two full passes, all 16 waves each
        wh_tile(Wf, Hf, Pd, Wf, Hf, n, true,  wv_i, wv_j, lr, lq, rowm, colm);
        wh_tile(Wf, Hf, Pd, Wf, Hf, n, false, wv_i, wv_j, lr, lq, rowm, colm);
      }
      mm64_mfma<false>(Pd, Pd, Pd, wv_i, wv_j, lr, lq, rowm, colm);
    }
  } else {
    for (int k = 0; k < 7; ++k) {
      const int n = 1 << k;
      if (n <= 16) {
        if (t < (n << 6)) {
          int r = t >> 6, ii = t & 63;
          double aw = 0.0, ah = 0.0;
#pragma unroll 4
          for (int c = 0; c < 64; ++c) {
            aw = fma(Pd[ii * 65 + c], (double)Wf[r * 65 + c], aw);
            ah = fma((double)Hf[r * 65 + c], Pd[c * 65 + ii], ah);
          }
          Wf[(n + r) * 65 + ii] = (float)aw;
          Hf[(n + r) * 65 + ii] = (float)ah;
        }
      } else if (n == 32) {
        const int r  = t >> 5;
        const int i2 = (t & 31) << 1;
        double w0 = 0, w1 = 0, h0 = 0, h1 = 0;
#pragma unroll 4
        for (int c = 0; c < 64; ++c) {
          double wr = (double)Wf[r * 65 + c];
          w0 = fma(wr, Pd[(i2 + 0) * 65 + c], w0);
          w1 = fma(wr, Pd[(i2 + 1) * 65 + c], w1);
          double hr = (double)Hf[r * 65 + c];
          h0 = fma(hr, Pd[c * 65 + i2 + 0], h0);
          h1 = fma(hr, Pd[c * 65 + i2 + 1], h1);
        }
        Wf[(32 + r) * 65 + i2 + 0] = (float)w0;
        Wf[(32 + r) * 65 + i2 + 1] = (float)w1;
        Hf[(32 + r) * 65 + i2 + 0] = (float)h0;
        Hf[(32 + r) * 65 + i2 + 1] = (float)h1;
      } else {  // n == 64
        const int r2 = tr2, i2 = tc2;
        double w00 = 0, w01 = 0, w10 = 0, w11 = 0;
        double h00 = 0, h01 = 0, h10 = 0, h11 = 0;
#pragma unroll 4
        for (int c = 0; c < 64; ++c) {
          double wa = (double)Wf[(r2 + 0) * 65 + c];
          double wb = (double)Wf[(r2 + 1) * 65 + c];
          double p0 = Pd[(i2 + 0) * 65 + c];
          double p1 = Pd[(i2 + 1) * 65 + c];
          w00 = fma(wa, p0, w00); w01 = fma(wa, p1, w01);
          w10 = fma(wb, p0, w10); w11 = fma(wb, p1, w11);
          double ha = (double)Hf[(r2 + 0) * 65 + c];
          double hb = (double)Hf[(r2 + 1) * 65 + c];
          double q0 = Pd[c * 65 + i2 + 0];
          double q1 = Pd[c * 65 + i2 + 1];
          h00 = fma(ha, q0, h00); h01 = fma(ha, q1, h01);
          h10 = fma(hb, q0, h10); h11 = fma(hb, q1, h11);
        }
        Wf[(64 + r2 + 0) * 65 + i2 + 0] = (float)w00;
        Wf[(64 + r2 + 0) * 65 + i2 + 1] = (float)w01;
        Wf[(64 + r2 + 1) * 65 + i2 + 0] = (float)w10;
        Wf[(64 + r2 + 1) * 65 + i2 + 1] = (float)w11;
        Hf[(64 + r2 + 0) * 65 + i2 + 0] = (float)h00;
        Hf[(64 + r2 + 0) * 65 + i2 + 1] = (float)h01;
        Hf[(64 + r2 + 1) * 65 + i2 + 0] = (float)h10;
        Hf[(64 + r2 + 1) * 65 + i2 + 1] = (float)h11;
      }
      mm64x2<false>(Pd, Pd, Pd, tr2, tc2);
    }
  }

  // Pd = Ab^128 = M (fp64) -> global for k_scan
  for (int idx = t; idx < 4096; idx += 1024)
    Mgd[idx] = Pd[(idx >> 6) * 65 + (idx & 63)];

  // K[r] = C . W[r]
  if (t < 128) {
    double s = 0.0;
    for (int c = 0; c < 64; ++c) s = fma((double)Cin[c], (double)Wf[t * 65 + c], s);
    Kf[t] = (float)s;
  }
  __syncthreads();

  // W -> global (dense 64-stride for k_chunkvec)
  for (int idx = t; idx < 8192; idx += 1024)
    Wg[idx] = Wf[(idx >> 6) * 65 + (idx & 63)];

  // G Toeplitz part: G[k][r] = K[r-k] (r>=k) + D*(k==r)
  const float Dval = Din[0];
  for (int idx = t; idx < 16384; idx += 1024) {
    int k = idx >> 7, r = idx & 127;
    float v = (r >= k) ? Kf[r - k] : 0.f;
    if (k == r) v += Dval;
    Gg[idx] = v;
  }
  // G cross-chunk part: G[128+i][r] = H[r][i]
  for (int idx = t; idx < 8192; idx += 1024) {
    int i = idx >> 7, r = idx & 127;
    Gg[(128 + i) * 128 + r] = Hf[r * 65 + i];
  }
}

// ---------------------------------------------------------------------------
// Kernel B: chunk input vectors  b[rc][i] = sum_k u[rc][k] * W[127-k][i]
// GEMM M=65536, N=64, K=128. Block = 128 rc-rows, 128 threads, 8x8 tiles.
// ---------------------------------------------------------------------------
__global__ __launch_bounds__(128) void k_chunkvec(
    const float* __restrict__ u, const float* __restrict__ Wg,
    float* __restrict__ bout)
{
  __shared__ float As[32 * 132];  // [kk][rcl], transposed u slice
  __shared__ float Bs[32 * 68];   // [kk][i]
  const int t = threadIdx.x;
  const int rc0 = blockIdx.x << 7;
  const int trow = (t >> 3) << 3;
  const int tcol = (t & 7) << 3;
  float acc[8][8];
#pragma unroll
  for (int i = 0; i < 8; ++i)
#pragma unroll
    for (int j = 0; j < 8; ++j) acc[i][j] = 0.f;

  for (int sl = 0; sl < 4; ++sl) {
    for (int it = t; it < 1024; it += 128) {
      int rcl = it >> 3, k4 = (it & 7) << 2;
      float4 v = *(const float4*)&u[((size_t)(rc0 + rcl) << 7) + (sl << 5) + k4];
      As[(k4 + 0) * 132 + rcl] = v.x;
      As[(k4 + 1) * 132 + rcl] = v.y;
      As[(k4 + 2) * 132 + rcl] = v.z;
      As[(k4 + 3) * 132 + rcl] = v.w;
    }
    for (int it = t; it < 512; it += 128) {
      int kk = it >> 4, i4 = (it & 15) << 2;
      *(float4*)&Bs[kk * 68 + i4] =
          *(const float4*)&Wg[((size_t)(127 - ((sl << 5) + kk)) << 6) + i4];
    }
    __syncthreads();
#pragma unroll 4
    for (int kk = 0; kk < 32; ++kk) {
      float av[8], bv[8];
      *(float4*)&av[0] = *(const float4*)&As[kk * 132 + trow];
      *(float4*)&av[4] = *(const float4*)&As[kk * 132 + trow + 4];
      *(float4*)&bv[0] = *(const float4*)&Bs[kk * 68 + tcol];
      *(float4*)&bv[4] = *(const float4*)&Bs[kk * 68 + tcol + 4];
#pragma unroll
      for (int i = 0; i < 8; ++i)
#pragma unroll
        for (int j = 0; j < 8; ++j) acc[i][j] = fmaf(av[i], bv[j], acc[i][j]);
    }
    __syncthreads();
  }
#pragma unroll
  for (int i = 0; i < 8; ++i) {
    size_t base = ((size_t)(rc0 + trow + i) << 6) + tcol;
    *(float4*)&bout[base]     = make_float4(acc[i][0], acc[i][1], acc[i][2], acc[i][3]);
    *(float4*)&bout[base + 4] = make_float4(acc[i][4], acc[i][5], acc[i][6], acc[i][7]);
  }
}

// ---------------------------------------------------------------------------
// Kernel C: per-row chunk-state scan in fp64. X_0 = 0; X_{j+1} = M X_j + b_j.
// br[j+1] prefetched so its global-load latency hides under the matvec.
// ---------------------------------------------------------------------------
__global__ __launch_bounds__(256) void k_scan(
    const double* __restrict__ Mg, const float* __restrict__ bv,
    float* __restrict__ Xg)
{
  __shared__ double xs[64];
  __shared__ double part[3 * 64];
  const int t = threadIdx.x;
  const int i = t & 63, q = t >> 6;   // q is wave-uniform
  double Mr[16];
#pragma unroll
  for (int c = 0; c < 16; ++c) Mr[c] = Mg[((size_t)i << 6) + (q << 4) + c];
  const float* br = bv + ((size_t)blockIdx.x << 13);
  float* Xr = Xg + ((size_t)blockIdx.x << 13);
  float bcur = 0.f, bnext = 0.f;
  if (t < 64) {
    xs[t] = 0.0;
    bcur = br[i];
  }
  __syncthreads();
  for (int j = 0; j < 128; ++j) {
    if (q == 0 && j < 127) bnext = br[((j + 1) << 6) + i];  // prefetch
    double s0 = 0, s1 = 0, s2 = 0, s3 = 0;
#pragma unroll
    for (int c = 0; c < 16; c += 4) {   // xs reads are wave-uniform broadcasts
      s0 = fma(Mr[c + 0], xs[(q << 4) + c + 0], s0);
      s1 = fma(Mr[c + 1], xs[(q << 4) + c + 1], s1);
      s2 = fma(Mr[c + 2], xs[(q << 4) + c + 2], s2);
      s3 = fma(Mr[c + 3], xs[(q << 4) + c + 3], s3);
    }
    double ps = (s0 + s1) + (s2 + s3);
    if (q) part[((q - 1) << 6) + i] = ps;
    __syncthreads();
    if (q == 0) {
      double xold = xs[i];
      Xr[(j << 6) + i] = (float)xold;                 // state at chunk start
      xs[i] = (double)bcur + ps + part[i] + part[64 + i] + part[128 + i];
      bcur = bnext;
    }
    __syncthreads();
  }
}

// ---------------------------------------------------------------------------
// Kernel D: main output GEMM. y[rc][r] = sum_{k<128} u[rc][k] G[k][r]
//                                       + sum_i X[rc][i] G[128+i][r]
// ---------------------------------------------------------------------------
__global__ __launch_bounds__(256) void k_main(
    const float* __restrict__ u, const float* __restrict__ Xg,
    const float* __restrict__ Gg, float* __restrict__ out)
{
  __shared__ float As[32 * 132];  // [kk][rcl]
  __shared__ float Bs[32 * 132];  // [kk][r]
  const int t = threadIdx.x;
  const int rc0 = blockIdx.x << 7;
  const int trow = (t >> 4) << 3;
  const int tcol = (t & 15) << 3;
  float acc[8][8];
#pragma unroll
  for (int i = 0; i < 8; ++i)
#pragma unroll
    for (int j = 0; j < 8; ++j) acc[i][j] = 0.f;

  for (int sl = 0; sl < 6; ++sl) {
    const int k0 = sl << 5;
    for (int it = t; it < 1024; it += 256) {
      int rcl = it >> 3, k4 = (it & 7) << 2;
      int kg = k0 + k4;
      float4 v;
      if (kg < 128)
        v = *(const float4*)&u[((size_t)(rc0 + rcl) << 7) + kg];
      else
        v = *(const float4*)&Xg[((size_t)(rc0 + rcl) << 6) + (kg - 128)];
      As[(k4 + 0) * 132 + rcl] = v.x;
      As[(k4 + 1) * 132 + rcl] = v.y;
      As[(k4 + 2) * 132 + rcl] = v.z;
      As[(k4 + 3) * 132 + rcl] = v.w;
    }
    for (int it = t; it < 1024; it += 256) {
      int kk = it >> 5, r4 = (it & 31) << 2;
      *(float4*)&Bs[kk * 132 + r4] = *(const float4*)&Gg[(size_t)(k0 + kk) * 128 + r4];
    }
    __syncthreads();
#pragma unroll 4
    for (int kk = 0; kk < 32; ++kk) {
      float av[8], bv[8];
      *(float4*)&av[0] = *(const float4*)&As[kk * 132 + trow];
      *(float4*)&av[4] = *(const float4*)&As[kk * 132 + trow + 4];
      *(float4*)&bv[0] = *(const float4*)&Bs[kk * 132 + tcol];
      *(float4*)&bv[4] = *(const float4*)&Bs[kk * 132 + tcol + 4];
#pragma unroll
      for (int i = 0; i < 8; ++i)
#pragma unroll
        for (int j = 0; j < 8; ++j) acc[i][j] = fmaf(av[i], bv[j], acc[i][j]);
    }
    __syncthreads();
  }
#pragma unroll
  for (int i = 0; i < 8; ++i) {
    size_t base = ((size_t)(rc0 + trow + i) << 7) + tcol;
    *(float4*)&out[base]     = make_float4(acc[i][0], acc[i][1], acc[i][2], acc[i][3]);
    *(float4*)&out[base + 4] = make_float4(acc[i][4], acc[i][5], acc[i][6], acc[i][7]);
  }
}

// ---------------------------------------------------------------------------
extern "C" void kernel_launch(void* const* d_in, const int* in_sizes, int n_in,
                              void* d_out, int out_size, void* d_ws, size_t ws_size,
                              hipStream_t stream) {
  (void)in_sizes; (void)n_in; (void)out_size; (void)ws_size;
  const float* u  = (const float*)d_in[0];
  const float* A  = (const float*)d_in[1];
  const float* Bv = (const float*)d_in[2];
  const float* Cv = (const float*)d_in[3];
  const float* Dv = (const float*)d_in[4];
  const float* ls = (const float*)d_in[5];
  float* out = (float*)d_out;
  float* ws  = (float*)d_ws;

  k_precomp<<<1, 1024, 0, stream>>>(A, Bv, Cv, Dv, ls, ws);
  k_chunkvec<<<512, 128, 0, stream>>>(u, ws + WS_W, ws + WS_BV);
  k_scan<<<512, 256, 0, stream>>>((const double*)(ws + WS_MD), ws + WS_BV, ws + WS_X);
  k_main<<<512, 256, 0, stream>>>(u, ws + WS_X, ws + WS_G, out);
}

// Round 5
// 220.477 us; speedup vs baseline: 1.6454x; 1.2473x over previous
//
#include <hip/hip_runtime.h>
#include <cstddef>

typedef double f64x4 __attribute__((ext_vector_type(4)));
typedef float  f32x4 __attribute__((ext_vector_type(4)));
typedef short  bf16x8 __attribute__((ext_vector_type(8)));   // 8 bf16 = 4 VGPRs

// Problem constants: N=64 state dim, L=16384 seq, BATCH=512, chunk m=128.
static constexpr int RCN = 512 * 128;   // 65536 (row, chunk) pairs

// ws layout (float offsets). WS_W region now holds Wt bf16 (64x128 ushort =
// 4096 floats <= 8192); WS_G holds Gt bf16 (128x192 ushort = 12288 <= 24576).
static constexpr size_t WS_W  = 0;
static constexpr size_t WS_G  = 8192;
static constexpr size_t WS_MD = 32768;   // M = Ab^128, 64x64 DOUBLE
static constexpr size_t WS_BV = 40960;   // chunk vectors b, RCN x 64 fp32
static constexpr size_t WS_X  = WS_BV + (size_t)RCN * 64;  // chunk states X

// fp32 -> bf16 round-to-nearest-even (finite inputs only)
__device__ __forceinline__ unsigned short f2bf(float f) {
  union { float f; unsigned u; } v; v.f = f;
  unsigned u = v.u + 0x7FFFu + ((v.u >> 16) & 1u);
  return (unsigned short)(u >> 16);
}

// ---------------------------------------------------------------------------
// f64 MFMA layout probe (verified working in round 4). Pure-register.
// ---------------------------------------------------------------------------
__device__ __forceinline__ double probeE(int i, int k) {
  return (double)(((i * 3 + k * 5) & 7) - 3);
}
__device__ __forceinline__ double probeF(int k, int j) {
  return (double)(((k * 7 + j * 2) & 7) - 4);
}

__device__ __forceinline__ bool probe_mfma_layout(int lr, int lq, int rowm[4], int* colm_out)
{
  f64x4 z; z[0] = 0.0; z[1] = 0.0; z[2] = 0.0; z[3] = 0.0;
  f64x4 p1 = __builtin_amdgcn_mfma_f64_16x16x4f64((double)lr, 1.0, z, 0, 0, 0);
  f64x4 p2 = __builtin_amdgcn_mfma_f64_16x16x4f64(1.0, (double)lr, z, 0, 0, 0);
  bool okl = true;
#pragma unroll
  for (int r = 0; r < 4; ++r) {
    int rr = (int)(p1[r] * 0.25 + 0.5);
    okl = okl && (p1[r] == 4.0 * (double)rr) && rr >= 0 && rr < 16;
    rowm[r] = rr & 15;
    okl = okl && (p2[r] == p2[0]);
  }
  int cc = (int)(p2[0] * 0.25 + 0.5);
  okl = okl && (p2[0] == 4.0 * (double)cc) && cc >= 0 && cc < 16;
  *colm_out = cc & 15;
  f64x4 d = __builtin_amdgcn_mfma_f64_16x16x4f64(probeE(lr, lq), probeF(lq, lr), z, 0, 0, 0);
#pragma unroll
  for (int r = 0; r < 4; ++r) {
    double ref = 0.0;
#pragma unroll
    for (int k = 0; k < 4; ++k) ref += probeE(rowm[r], k) * probeF(k, cc & 15);
    okl = okl && (d[r] == ref);
  }
  return __all(okl) != 0;
}

// ---------------------------------------------------------------------------
// In-place 64x64x64 fp64 matmul in LDS via v_mfma_f64_16x16x4_f64.
// ---------------------------------------------------------------------------
template<bool ADD>
__device__ __forceinline__ void mm64_mfma(const double* A, const double* B, double* D,
                                          int wi, int wj, int lr, int lq,
                                          const int rowm[4], int colm)
{
  f64x4 acc;
  if (ADD) {
#pragma unroll
    for (int r = 0; r < 4; ++r)
      acc[r] = D[(wi * 16 + rowm[r]) * 65 + wj * 16 + colm];
  } else {
    acc[0] = 0.0; acc[1] = 0.0; acc[2] = 0.0; acc[3] = 0.0;
  }
#pragma unroll
  for (int kb = 0; kb < 16; ++kb) {
    double a = A[(wi * 16 + lr) * 65 + kb * 4 + lq];
    double b = B[(kb * 4 + lq) * 65 + wj * 16 + lr];
    acc = __builtin_amdgcn_mfma_f64_16x16x4f64(a, b, acc, 0, 0, 0);
  }
  __syncthreads();
#pragma unroll
  for (int r = 0; r < 4; ++r)
    D[(wi * 16 + rowm[r]) * 65 + wj * 16 + colm] = acc[r];
  __syncthreads();
}

// One 16x16 tile of the W/H log-doubling expansion (MFMA, probed maps).
__device__ __forceinline__ void wh_tile(const float* Wf, const float* Hf,
                                        const double* Pd, float* Wo, float* Ho,
                                        int n, bool isW, int wi, int wj,
                                        int lr, int lq, const int rowm[4], int colm)
{
  f64x4 acc;
  acc[0] = 0.0; acc[1] = 0.0; acc[2] = 0.0; acc[3] = 0.0;
#pragma unroll
  for (int kb = 0; kb < 16; ++kb) {
    double a, b;
    if (isW) {
      a = (double)Wf[(wi * 16 + lr) * 65 + kb * 4 + lq];
      b = Pd[(wj * 16 + lr) * 65 + kb * 4 + lq];     // P^T fragment
    } else {
      a = (double)Hf[(wi * 16 + lr) * 65 + kb * 4 + lq];
      b = Pd[(kb * 4 + lq) * 65 + wj * 16 + lr];     // P fragment
    }
    acc = __builtin_amdgcn_mfma_f64_16x16x4f64(a, b, acc, 0, 0, 0);
  }
#pragma unroll
  for (int r = 0; r < 4; ++r) {
    int drow = wi * 16 + rowm[r];
    if (drow < n) {
      if (isW) Wo[(n + drow) * 65 + wj * 16 + colm] = (float)acc[r];
      else     Ho[(n + drow) * 65 + wj * 16 + colm] = (float)acc[r];
    }
  }
}

// VALU fallback matmul (known-passing round-2 path).
template<bool ADD>
__device__ __forceinline__ void mm64x2(const double* A, const double* B, double* D,
                                       int tr2, int tc2)
{
  double a00 = 0, a01 = 0, a10 = 0, a11 = 0;
#pragma unroll 8
  for (int c = 0; c < 64; ++c) {
    double av0 = A[(tr2 + 0) * 65 + c];
    double av1 = A[(tr2 + 1) * 65 + c];
    double bv0 = B[c * 65 + tc2 + 0];
    double bv1 = B[c * 65 + tc2 + 1];
    a00 = fma(av0, bv0, a00); a01 = fma(av0, bv1, a01);
    a10 = fma(av1, bv0, a10); a11 = fma(av1, bv1, a11);
  }
  double o00, o01, o10, o11;
  if (ADD) {
    o00 = D[(tr2 + 0) * 65 + tc2 + 0]; o01 = D[(tr2 + 0) * 65 + tc2 + 1];
    o10 = D[(tr2 + 1) * 65 + tc2 + 0]; o11 = D[(tr2 + 1) * 65 + tc2 + 1];
  }
  __syncthreads();
  D[(tr2 + 0) * 65 + tc2 + 0] = ADD ? (o00 + a00) : a00;
  D[(tr2 + 0) * 65 + tc2 + 1] = ADD ? (o01 + a01) : a01;
  D[(tr2 + 1) * 65 + tc2 + 0] = ADD ? (o10 + a10) : a10;
  D[(tr2 + 1) * 65 + tc2 + 1] = ADD ? (o11 + a11) : a11;
  __syncthreads();
}

// ---------------------------------------------------------------------------
// Kernel A: discretize + build all weights. 1 block x 1024 threads (16 waves).
// Epilogue now emits bf16 pre-transposed weights for the MFMA GEMMs:
//   Wt[i][k] = bf16(W[127-k][i])   (64x128)  -> ws+WS_W as ushort
//   Gt[r][k] = bf16(G[k][r])       (128x192) -> ws+WS_G as ushort
// ---------------------------------------------------------------------------
__global__ __launch_bounds__(1024) void k_precomp(
    const float* __restrict__ Ain, const float* __restrict__ Bin,
    const float* __restrict__ Cin, const float* __restrict__ Din,
    const float* __restrict__ LS, float* ws)
{
  __shared__ double Xd[64 * 65];
  __shared__ double Pd[64 * 65];
  __shared__ float  Wf[128 * 65];
  __shared__ float  Hf[128 * 65];
  __shared__ float  Kf[128];

  const int t    = threadIdx.x;
  const int wave = t >> 6;
  const int lane = t & 63;
  const int lr   = lane & 15;
  const int lq   = lane >> 4;
  const int wv_i = wave >> 2;
  const int wv_j = wave & 3;
  const int tr2  = (t >> 5) << 1;
  const int tc2  = (t & 31) << 1;

  int rowm[4]; int colm;
  const bool use_mfma = probe_mfma_layout(lr, lq, rowm, &colm);

  unsigned short* Wtg = (unsigned short*)(ws + WS_W);
  unsigned short* Gtg = (unsigned short*)(ws + WS_G);
  double* Mgd = (double*)(ws + WS_MD);

  const double step = exp((double)LS[0]);
  const double h = 0.5 * step;

  for (int idx = t; idx < 4096; idx += 1024) {
    int i = idx >> 6, j = idx & 63;
    double a = h * (double)Ain[idx];
    Xd[i * 65 + j] = a;
    Pd[i * 65 + j] = a + ((i == j) ? 1.0 : 0.0);
  }
  __syncthreads();

  // Product-form Neumann: Z = sum_{j=0}^{15} X^j (||X||^16 <= 1e-16)
  if (use_mfma) {
    for (int k = 0; k < 3; ++k) {
      mm64_mfma<false>(Xd, Xd, Xd, wv_i, wv_j, lr, lq, rowm, colm);
      mm64_mfma<true >(Pd, Xd, Pd, wv_i, wv_j, lr, lq, rowm, colm);
    }
  } else {
    for (int k = 0; k < 3; ++k) {
      mm64x2<false>(Xd, Xd, Xd, tr2, tc2);
      mm64x2<true >(Pd, Xd, Pd, tr2, tc2);
    }
  }

  // Pd = N1. Bb = step * N1 @ B  -> W[0]
  if (t < 64) {
    double bb = 0.0;
    for (int c = 0; c < 64; ++c) bb = fma(Pd[t * 65 + c], (double)Bin[c], bb);
    Wf[t] = (float)(bb * step);
  }
  __syncthreads();

  // Ab = 2*N1 - I (in place)
  for (int idx = t; idx < 4096; idx += 1024) {
    int i = idx >> 6, j = idx & 63;
    Pd[i * 65 + j] = 2.0 * Pd[i * 65 + j] - ((i == j) ? 1.0 : 0.0);
  }
  __syncthreads();

  // H[0] = C @ Ab
  if (t < 64) {
    double hh = 0.0;
    for (int c = 0; c < 64; ++c) hh = fma((double)Cin[c], Pd[c * 65 + t], hh);
    Hf[t] = (float)hh;
  }
  __syncthreads();

  // Log-doubling of W/H; P <- P*P shared with the M = Ab^128 chain.
  if (use_mfma) {
    for (int k = 0; k < 7; ++k) {
      const int n     = 1 << k;
      const int tpm   = (n + 15) >> 4;
      const int tiles = tpm << 2;
      if (tiles <= 8) {
        if (wave < 2 * tiles) {
          const bool isW = wave < tiles;
          const int  w   = isW ? wave : wave - tiles;
          wh_tile(Wf, Hf, Pd, Wf, Hf, n, isW, w >> 2, w & 3, lr, lq, rowm, colm);
        }
      } else {
        wh_tile(Wf, Hf, Pd, Wf, Hf, n, true,  wv_i, wv_j, lr, lq, rowm, colm);
        wh_tile(Wf, Hf, Pd, Wf, Hf, n, false, wv_i, wv_j, lr, lq, rowm, colm);
      }
      mm64_mfma<false>(Pd, Pd, Pd, wv_i, wv_j, lr, lq, rowm, colm);
    }
  } else {
    for (int k = 0; k < 7; ++k) {
      const int n = 1 << k;
      if (n <= 16) {
        if (t < (n << 6)) {
          int r = t >> 6, ii = t & 63;
          double aw = 0.0, ah = 0.0;
#pragma unroll 4
          for (int c = 0; c < 64; ++c) {
            aw = fma(Pd[ii * 65 + c], (double)Wf[r * 65 + c], aw);
            ah = fma((double)Hf[r * 65 + c], Pd[c * 65 + ii], ah);
          }
          Wf[(n + r) * 65 + ii] = (float)aw;
          Hf[(n + r) * 65 + ii] = (float)ah;
        }
      } else if (n == 32) {
        const int r  = t >> 5;
        const int i2 = (t & 31) << 1;
        double w0 = 0, w1 = 0, h0 = 0, h1 = 0;
#pragma unroll 4
        for (int c = 0; c < 64; ++c) {
          double wr = (double)Wf[r * 65 + c];
          w0 = fma(wr, Pd[(i2 + 0) * 65 + c], w0);
          w1 = fma(wr, Pd[(i2 + 1) * 65 + c], w1);
          double hr = (double)Hf[r * 65 + c];
          h0 = fma(hr, Pd[c * 65 + i2 + 0], h0);
          h1 = fma(hr, Pd[c * 65 + i2 + 1], h1);
        }
        Wf[(32 + r) * 65 + i2 + 0] = (float)w0;
        Wf[(32 + r) * 65 + i2 + 1] = (float)w1;
        Hf[(32 + r) * 65 + i2 + 0] = (float)h0;
        Hf[(32 + r) * 65 + i2 + 1] = (float)h1;
      } else {
        const int r2 = tr2, i2 = tc2;
        double w00 = 0, w01 = 0, w10 = 0, w11 = 0;
        double h00 = 0, h01 = 0, h10 = 0, h11 = 0;
#pragma unroll 4
        for (int c = 0; c < 64; ++c) {
          double wa = (double)Wf[(r2 + 0) * 65 + c];
          double wb = (double)Wf[(r2 + 1) * 65 + c];
          double p0 = Pd[(i2 + 0) * 65 + c];
          double p1 = Pd[(i2 + 1) * 65 + c];
          w00 = fma(wa, p0, w00); w01 = fma(wa, p1, w01);
          w10 = fma(wb, p0, w10); w11 = fma(wb, p1, w11);
          double ha = (double)Hf[(r2 + 0) * 65 + c];
          double hb = (double)Hf[(r2 + 1) * 65 + c];
          double q0 = Pd[c * 65 + i2 + 0];
          double q1 = Pd[c * 65 + i2 + 1];
          h00 = fma(ha, q0, h00); h01 = fma(ha, q1, h01);
          h10 = fma(hb, q0, h10); h11 = fma(hb, q1, h11);
        }
        Wf[(64 + r2 + 0) * 65 + i2 + 0] = (float)w00;
        Wf[(64 + r2 + 0) * 65 + i2 + 1] = (float)w01;
        Wf[(64 + r2 + 1) * 65 + i2 + 0] = (float)w10;
        Wf[(64 + r2 + 1) * 65 + i2 + 1] = (float)w11;
        Hf[(64 + r2 + 0) * 65 + i2 + 0] = (float)h00;
        Hf[(64 + r2 + 0) * 65 + i2 + 1] = (float)h01;
        Hf[(64 + r2 + 1) * 65 + i2 + 0] = (float)h10;
        Hf[(64 + r2 + 1) * 65 + i2 + 1] = (float)h11;
      }
      mm64x2<false>(Pd, Pd, Pd, tr2, tc2);
    }
  }

  // Pd = Ab^128 = M (fp64) -> global for k_scan
  for (int idx = t; idx < 4096; idx += 1024)
    Mgd[idx] = Pd[(idx >> 6) * 65 + (idx & 63)];

  // K[r] = C . W[r]
  if (t < 128) {
    double s = 0.0;
    for (int c = 0; c < 64; ++c) s = fma((double)Cin[c], (double)Wf[t * 65 + c], s);
    Kf[t] = (float)s;
  }
  __syncthreads();

  // Wt[i][k] = bf16(W[127-k][i])  (64 x 128)
  for (int idx = t; idx < 8192; idx += 1024) {
    int i = idx >> 7, kk = idx & 127;
    Wtg[idx] = f2bf(Wf[(127 - kk) * 65 + i]);
  }

  // Gt[r][k] bf16, stride 192. Toeplitz part (k<128): K[r-k] + D*(k==r).
  const float Dval = Din[0];
  for (int idx = t; idx < 16384; idx += 1024) {
    int r = idx >> 7, kg = idx & 127;
    float v = (r >= kg) ? Kf[r - kg] : 0.f;
    if (kg == r) v += Dval;
    Gtg[r * 192 + kg] = f2bf(v);
  }
  // Cross-chunk part: Gt[r][128+i] = bf16(H[r][i]).
  for (int idx = t; idx < 8192; idx += 1024) {
    int r = idx >> 6, i = idx & 63;
    Gtg[r * 192 + 128 + i] = f2bf(Hf[r * 65 + i]);
  }
}

// ---------------------------------------------------------------------------
// Kernel B: chunk input vectors via bf16 MFMA.
//   b[rc][i] = sum_k u[rc][k] * Wt[i][k],  M=65536, N=64, K=128.
// Block: 128 rc x 64 cols, 256 threads (4 waves). Wave w: rows 32w..32w+31
// (2 row-tiles) x 4 col-tiles. K = 4 slices of 32 (one MFMA K-step each).
// ---------------------------------------------------------------------------
__global__ __launch_bounds__(256) void k_chunkvec(
    const float* __restrict__ u, const unsigned short* __restrict__ Wt,
    float* __restrict__ bout)
{
  __shared__ unsigned short Bs[64 * 136];  // Wt[i][k], stride 136 (16B-mult)
  __shared__ unsigned short As[128 * 40];  // u slice [rcl][kk], stride 40
  const int t = threadIdx.x;
  const int rc0 = blockIdx.x << 7;
  const int w  = t >> 6;
  const int lane = t & 63;
  const int lr = lane & 15, lq = lane >> 4;

  // Stage Wt (full K) as u32 copies.
  {
    const unsigned* src = (const unsigned*)Wt;
    unsigned* dst = (unsigned*)Bs;
    for (int idx = t; idx < 4096; idx += 256) {
      int r = idx >> 6, c = idx & 63;
      dst[r * 68 + c] = src[idx];
    }
  }
  // Stage As slice 0.
  for (int it = t; it < 1024; it += 256) {
    int rcl = it >> 3, k4 = (it & 7) << 2;
    float4 v = *(const float4*)&u[((size_t)(rc0 + rcl) << 7) + k4];
    ushort4 s;
    s.x = f2bf(v.x); s.y = f2bf(v.y); s.z = f2bf(v.z); s.w = f2bf(v.w);
    *(ushort4*)&As[rcl * 40 + k4] = s;
  }
  __syncthreads();

  f32x4 acc[2][4];
#pragma unroll
  for (int i = 0; i < 2; ++i)
#pragma unroll
    for (int j = 0; j < 4; ++j) { acc[i][j][0] = 0.f; acc[i][j][1] = 0.f; acc[i][j][2] = 0.f; acc[i][j][3] = 0.f; }

  for (int sl = 0; sl < 4; ++sl) {
    bf16x8 av[2], bv[4];
#pragma unroll
    for (int ti = 0; ti < 2; ++ti)
      av[ti] = *(const bf16x8*)&As[(w * 32 + ti * 16 + lr) * 40 + lq * 8];
#pragma unroll
    for (int tj = 0; tj < 4; ++tj)
      bv[tj] = *(const bf16x8*)&Bs[(tj * 16 + lr) * 136 + sl * 32 + lq * 8];
#pragma unroll
    for (int ti = 0; ti < 2; ++ti)
#pragma unroll
      for (int tj = 0; tj < 4; ++tj)
        acc[ti][tj] = __builtin_amdgcn_mfma_f32_16x16x32_bf16(av[ti], bv[tj], acc[ti][tj], 0, 0, 0);
    if (sl < 3) {
      __syncthreads();
      for (int it = t; it < 1024; it += 256) {
        int rcl = it >> 3, k4 = (it & 7) << 2;
        float4 v = *(const float4*)&u[((size_t)(rc0 + rcl) << 7) + ((sl + 1) << 5) + k4];
        ushort4 s;
        s.x = f2bf(v.x); s.y = f2bf(v.y); s.z = f2bf(v.z); s.w = f2bf(v.w);
        *(ushort4*)&As[rcl * 40 + k4] = s;
      }
      __syncthreads();
    }
  }

  // C/D: col = lane&15, row = (lane>>4)*4 + reg  [m89-verified]
#pragma unroll
  for (int ti = 0; ti < 2; ++ti)
#pragma unroll
    for (int tj = 0; tj < 4; ++tj)
#pragma unroll
      for (int r = 0; r < 4; ++r) {
        int row = rc0 + w * 32 + ti * 16 + lq * 4 + r;
        bout[((size_t)row << 6) + tj * 16 + lr] = acc[ti][tj][r];
      }
}

// ---------------------------------------------------------------------------
// Kernel C: per-row chunk-state scan, ONE WAVE per row, fp32, M in registers.
// X_0 = 0; X_{j+1} = M X_j + b_j. Lane i holds row i of M (64 fp32 regs).
// Per iter: 16 uniform ds_read_b128 of x + 64 v_fma_f32; barriers are
// single-wave (cheap). Replaces the 4-wave 2-barrier LDS-reduction version
// (60.7us, VALUBusy 13.7% -- serial-latency bound at ~1140 cyc/iter).
// fp32 is safe: scan is linear; bf16-b error (0.3% rel) dominates.
// ---------------------------------------------------------------------------
__global__ __launch_bounds__(64) void k_scan(
    const double* __restrict__ Mg, const float* __restrict__ bv,
    float* __restrict__ Xg)
{
  __shared__ float xs[64];
  const int lane = threadIdx.x;
  float Mr[64];
#pragma unroll
  for (int c = 0; c < 64; ++c)
    Mr[c] = (float)Mg[((size_t)lane << 6) + c];
  const float* br = bv + ((size_t)blockIdx.x << 13);
  float* Xr = Xg + ((size_t)blockIdx.x << 13);
  xs[lane] = 0.f;
  float bcur = br[lane];
  __syncthreads();
  for (int j = 0; j < 128; ++j) {
    float bnext = (j < 127) ? br[((j + 1) << 6) + lane] : 0.f;
    float y0 = 0.f, y1 = 0.f, y2 = 0.f, y3 = 0.f;
#pragma unroll
    for (int c4 = 0; c4 < 16; ++c4) {
      float4 xv = *(const float4*)&xs[c4 << 2];   // wave-uniform broadcast
      y0 = fmaf(Mr[c4 * 4 + 0], xv.x, y0);
      y1 = fmaf(Mr[c4 * 4 + 1], xv.y, y1);
      y2 = fmaf(Mr[c4 * 4 + 2], xv.z, y2);
      y3 = fmaf(Mr[c4 * 4 + 3], xv.w, y3);
    }
    float xold = xs[lane];
    Xr[(j << 6) + lane] = xold;                   // state at chunk start
    float xnew = bcur + ((y0 + y1) + (y2 + y3));
    __syncthreads();                              // all xs reads done
    xs[lane] = xnew;
    __syncthreads();                              // writes visible
    bcur = bnext;
  }
}

// ---------------------------------------------------------------------------
// Kernel D: main output GEMM via bf16 MFMA.
//   y[rc][r] = sum_{k<192} As[rc][k] * Gt[r][k]
//   (As = [u | X], Gt = fused Toeplitz+cross-chunk weights, bf16)
// Block: 128 rc x 128 r, 256 threads (4 waves). Wave w: rows 32w..32w+31
// (2 row-tiles) x 8 col-tiles. K = 6 slices of 32.
// ---------------------------------------------------------------------------
__global__ __launch_bounds__(256) void k_main(
    const float* __restrict__ u, const float* __restrict__ Xg,
    const unsigned short* __restrict__ Gt, float* __restrict__ out)
{
  __shared__ unsigned short Gs[128 * 200];  // Gt[r][k], stride 200 (16B-mult)
  __shared__ unsigned short As[128 * 40];   // [rcl][kk] slice, stride 40
  const int t = threadIdx.x;
  const int rc0 = blockIdx.x << 7;
  const int w  = t >> 6;
  const int lane = t & 63;
  const int lr = lane & 15, lq = lane >> 4;

  // Stage Gt (full 128x192) as u32 copies.
  {
    const unsigned* src = (const unsigned*)Gt;
    unsigned* dst = (unsigned*)Gs;
    for (int idx = t; idx < 12288; idx += 256) {
      int r = idx / 96, c = idx - r * 96;
      dst[r * 100 + c] = src[idx];
    }
  }
  // Stage As slice 0 (pure u).
  for (int it = t; it < 1024; it += 256) {
    int rcl = it >> 3, k4 = (it & 7) << 2;
    float4 v = *(const float4*)&u[((size_t)(rc0 + rcl) << 7) + k4];
    ushort4 s;
    s.x = f2bf(v.x); s.y = f2bf(v.y); s.z = f2bf(v.z); s.w = f2bf(v.w);
    *(ushort4*)&As[rcl * 40 + k4] = s;
  }
  __syncthreads();

  f32x4 acc[2][8];
#pragma unroll
  for (int i = 0; i < 2; ++i)
#pragma unroll
    for (int j = 0; j < 8; ++j) { acc[i][j][0] = 0.f; acc[i][j][1] = 0.f; acc[i][j][2] = 0.f; acc[i][j][3] = 0.f; }

  for (int sl = 0; sl < 6; ++sl) {
    bf16x8 av[2], bv[8];
#pragma unroll
    for (int ti = 0; ti < 2; ++ti)
      av[ti] = *(const bf16x8*)&As[(w * 32 + ti * 16 + lr) * 40 + lq * 8];
#pragma unroll
    for (int tj = 0; tj < 8; ++tj)
      bv[tj] = *(const bf16x8*)&Gs[(tj * 16 + lr) * 200 + sl * 32 + lq * 8];
#pragma unroll
    for (int ti = 0; ti < 2; ++ti)
#pragma unroll
      for (int tj = 0; tj < 8; ++tj)
        acc[ti][tj] = __builtin_amdgcn_mfma_f32_16x16x32_bf16(av[ti], bv[tj], acc[ti][tj], 0, 0, 0);
    if (sl < 5) {
      __syncthreads();
      for (int it = t; it < 1024; it += 256) {
        int rcl = it >> 3, k4 = (it & 7) << 2;
        int kg = ((sl + 1) << 5) + k4;
        float4 v;
        if (kg < 128)
          v = *(const float4*)&u[((size_t)(rc0 + rcl) << 7) + kg];
        else
          v = *(const float4*)&Xg[((size_t)(rc0 + rcl) << 6) + (kg - 128)];
        ushort4 s;
        s.x = f2bf(v.x); s.y = f2bf(v.y); s.z = f2bf(v.z); s.w = f2bf(v.w);
        *(ushort4*)&As[rcl * 40 + k4] = s;
      }
      __syncthreads();
    }
  }

  // C/D: col = lane&15, row = (lane>>4)*4 + reg  [m89-verified]
#pragma unroll
  for (int ti = 0; ti < 2; ++ti)
#pragma unroll
    for (int tj = 0; tj < 8; ++tj)
#pragma unroll
      for (int r = 0; r < 4; ++r) {
        int row = rc0 + w * 32 + ti * 16 + lq * 4 + r;
        out[((size_t)row << 7) + tj * 16 + lr] = acc[ti][tj][r];
      }
}

// ---------------------------------------------------------------------------
extern "C" void kernel_launch(void* const* d_in, const int* in_sizes, int n_in,
                              void* d_out, int out_size, void* d_ws, size_t ws_size,
                              hipStream_t stream) {
  (void)in_sizes; (void)n_in; (void)out_size; (void)ws_size;
  const float* u  = (const float*)d_in[0];
  const float* A  = (const float*)d_in[1];
  const float* Bv = (const float*)d_in[2];
  const float* Cv = (const float*)d_in[3];
  const float* Dv = (const float*)d_in[4];
  const float* ls = (const float*)d_in[5];
  float* out = (float*)d_out;
  float* ws  = (float*)d_ws;

  k_precomp<<<1, 1024, 0, stream>>>(A, Bv, Cv, Dv, ls, ws);
  k_chunkvec<<<512, 256, 0, stream>>>(u, (const unsigned short*)(ws + WS_W), ws + WS_BV);
  k_scan<<<512, 64, 0, stream>>>((const double*)(ws + WS_MD), ws + WS_BV, ws + WS_X);
  k_main<<<512, 256, 0, stream>>>(u, ws + WS_X, (const unsigned short*)(ws + WS_G), out);
}

// Round 6
// 211.068 us; speedup vs baseline: 1.7188x; 1.0446x over previous
//
#include <hip/hip_runtime.h>
#include <cstddef>

typedef double f64x4 __attribute__((ext_vector_type(4)));
typedef float  f32x4 __attribute__((ext_vector_type(4)));
typedef short  bf16x8 __attribute__((ext_vector_type(8)));   // 8 bf16 = 4 VGPRs

// Problem constants: N=64 state dim, L=16384 seq, BATCH=512, chunk m=128.
static constexpr int RCN = 512 * 128;   // 65536 (row, chunk) pairs

// ws layout (float offsets). WS_W holds Wt bf16 (64x128 ushort); WS_G holds
// Gt bf16 (128x192 ushort). WS_MD now holds M fp32 [0..4095] + M^2 fp32
// [4096..8191] for the depth-halved scan.
static constexpr size_t WS_W  = 0;
static constexpr size_t WS_G  = 8192;
static constexpr size_t WS_MD = 32768;
static constexpr size_t WS_BV = 40960;   // chunk vectors b, RCN x 64 fp32
static constexpr size_t WS_X  = WS_BV + (size_t)RCN * 64;  // chunk states X

// fp32 -> bf16 round-to-nearest-even (finite inputs only)
__device__ __forceinline__ unsigned short f2bf(float f) {
  union { float f; unsigned u; } v; v.f = f;
  unsigned u = v.u + 0x7FFFu + ((v.u >> 16) & 1u);
  return (unsigned short)(u >> 16);
}

// ---------------------------------------------------------------------------
// f64 MFMA layout probe (verified working in rounds 4-5). Pure-register.
// ---------------------------------------------------------------------------
__device__ __forceinline__ double probeE(int i, int k) {
  return (double)(((i * 3 + k * 5) & 7) - 3);
}
__device__ __forceinline__ double probeF(int k, int j) {
  return (double)(((k * 7 + j * 2) & 7) - 4);
}

__device__ __forceinline__ bool probe_mfma_layout(int lr, int lq, int rowm[4], int* colm_out)
{
  f64x4 z; z[0] = 0.0; z[1] = 0.0; z[2] = 0.0; z[3] = 0.0;
  f64x4 p1 = __builtin_amdgcn_mfma_f64_16x16x4f64((double)lr, 1.0, z, 0, 0, 0);
  f64x4 p2 = __builtin_amdgcn_mfma_f64_16x16x4f64(1.0, (double)lr, z, 0, 0, 0);
  bool okl = true;
#pragma unroll
  for (int r = 0; r < 4; ++r) {
    int rr = (int)(p1[r] * 0.25 + 0.5);
    okl = okl && (p1[r] == 4.0 * (double)rr) && rr >= 0 && rr < 16;
    rowm[r] = rr & 15;
    okl = okl && (p2[r] == p2[0]);
  }
  int cc = (int)(p2[0] * 0.25 + 0.5);
  okl = okl && (p2[0] == 4.0 * (double)cc) && cc >= 0 && cc < 16;
  *colm_out = cc & 15;
  f64x4 d = __builtin_amdgcn_mfma_f64_16x16x4f64(probeE(lr, lq), probeF(lq, lr), z, 0, 0, 0);
#pragma unroll
  for (int r = 0; r < 4; ++r) {
    double ref = 0.0;
#pragma unroll
    for (int k = 0; k < 4; ++k) ref += probeE(rowm[r], k) * probeF(k, cc & 15);
    okl = okl && (d[r] == ref);
  }
  return __all(okl) != 0;
}

// ---------------------------------------------------------------------------
// In-place 64x64x64 fp64 matmul in LDS via v_mfma_f64_16x16x4_f64.
// ---------------------------------------------------------------------------
template<bool ADD>
__device__ __forceinline__ void mm64_mfma(const double* A, const double* B, double* D,
                                          int wi, int wj, int lr, int lq,
                                          const int rowm[4], int colm)
{
  f64x4 acc;
  if (ADD) {
#pragma unroll
    for (int r = 0; r < 4; ++r)
      acc[r] = D[(wi * 16 + rowm[r]) * 65 + wj * 16 + colm];
  } else {
    acc[0] = 0.0; acc[1] = 0.0; acc[2] = 0.0; acc[3] = 0.0;
  }
#pragma unroll
  for (int kb = 0; kb < 16; ++kb) {
    double a = A[(wi * 16 + lr) * 65 + kb * 4 + lq];
    double b = B[(kb * 4 + lq) * 65 + wj * 16 + lr];
    acc = __builtin_amdgcn_mfma_f64_16x16x4f64(a, b, acc, 0, 0, 0);
  }
  __syncthreads();
#pragma unroll
  for (int r = 0; r < 4; ++r)
    D[(wi * 16 + rowm[r]) * 65 + wj * 16 + colm] = acc[r];
  __syncthreads();
}

// One 16x16 tile of the W/H log-doubling expansion (MFMA, probed maps).
__device__ __forceinline__ void wh_tile(const float* Wf, const float* Hf,
                                        const double* Pd, float* Wo, float* Ho,
                                        int n, bool isW, int wi, int wj,
                                        int lr, int lq, const int rowm[4], int colm)
{
  f64x4 acc;
  acc[0] = 0.0; acc[1] = 0.0; acc[2] = 0.0; acc[3] = 0.0;
#pragma unroll
  for (int kb = 0; kb < 16; ++kb) {
    double a, b;
    if (isW) {
      a = (double)Wf[(wi * 16 + lr) * 65 + kb * 4 + lq];
      b = Pd[(wj * 16 + lr) * 65 + kb * 4 + lq];     // P^T fragment
    } else {
      a = (double)Hf[(wi * 16 + lr) * 65 + kb * 4 + lq];
      b = Pd[(kb * 4 + lq) * 65 + wj * 16 + lr];     // P fragment
    }
    acc = __builtin_amdgcn_mfma_f64_16x16x4f64(a, b, acc, 0, 0, 0);
  }
#pragma unroll
  for (int r = 0; r < 4; ++r) {
    int drow = wi * 16 + rowm[r];
    if (drow < n) {
      if (isW) Wo[(n + drow) * 65 + wj * 16 + colm] = (float)acc[r];
      else     Ho[(n + drow) * 65 + wj * 16 + colm] = (float)acc[r];
    }
  }
}

// VALU fallback matmul (known-passing round-2 path).
template<bool ADD>
__device__ __forceinline__ void mm64x2(const double* A, const double* B, double* D,
                                       int tr2, int tc2)
{
  double a00 = 0, a01 = 0, a10 = 0, a11 = 0;
#pragma unroll 8
  for (int c = 0; c < 64; ++c) {
    double av0 = A[(tr2 + 0) * 65 + c];
    double av1 = A[(tr2 + 1) * 65 + c];
    double bv0 = B[c * 65 + tc2 + 0];
    double bv1 = B[c * 65 + tc2 + 1];
    a00 = fma(av0, bv0, a00); a01 = fma(av0, bv1, a01);
    a10 = fma(av1, bv0, a10); a11 = fma(av1, bv1, a11);
  }
  double o00, o01, o10, o11;
  if (ADD) {
    o00 = D[(tr2 + 0) * 65 + tc2 + 0]; o01 = D[(tr2 + 0) * 65 + tc2 + 1];
    o10 = D[(tr2 + 1) * 65 + tc2 + 0]; o11 = D[(tr2 + 1) * 65 + tc2 + 1];
  }
  __syncthreads();
  D[(tr2 + 0) * 65 + tc2 + 0] = ADD ? (o00 + a00) : a00;
  D[(tr2 + 0) * 65 + tc2 + 1] = ADD ? (o01 + a01) : a01;
  D[(tr2 + 1) * 65 + tc2 + 0] = ADD ? (o10 + a10) : a10;
  D[(tr2 + 1) * 65 + tc2 + 1] = ADD ? (o11 + a11) : a11;
  __syncthreads();
}

// ---------------------------------------------------------------------------
// Kernel A: discretize + build all weights. 1 block x 1024 threads (16 waves).
// Emits: Wt bf16, Gt bf16, and M / M^2 fp32 (for the depth-halved scan).
// ---------------------------------------------------------------------------
__global__ __launch_bounds__(1024) void k_precomp(
    const float* __restrict__ Ain, const float* __restrict__ Bin,
    const float* __restrict__ Cin, const float* __restrict__ Din,
    const float* __restrict__ LS, float* ws)
{
  __shared__ double Xd[64 * 65];
  __shared__ double Pd[64 * 65];
  __shared__ float  Wf[128 * 65];
  __shared__ float  Hf[128 * 65];
  __shared__ float  Kf[128];

  const int t    = threadIdx.x;
  const int wave = t >> 6;
  const int lane = t & 63;
  const int lr   = lane & 15;
  const int lq   = lane >> 4;
  const int wv_i = wave >> 2;
  const int wv_j = wave & 3;
  const int tr2  = (t >> 5) << 1;
  const int tc2  = (t & 31) << 1;

  int rowm[4]; int colm;
  const bool use_mfma = probe_mfma_layout(lr, lq, rowm, &colm);

  unsigned short* Wtg = (unsigned short*)(ws + WS_W);
  unsigned short* Gtg = (unsigned short*)(ws + WS_G);
  float* Mf = ws + WS_MD;   // M fp32 [0..4095], M^2 fp32 [4096..8191]

  const double step = exp((double)LS[0]);
  const double h = 0.5 * step;

  for (int idx = t; idx < 4096; idx += 1024) {
    int i = idx >> 6, j = idx & 63;
    double a = h * (double)Ain[idx];
    Xd[i * 65 + j] = a;
    Pd[i * 65 + j] = a + ((i == j) ? 1.0 : 0.0);
  }
  __syncthreads();

  // Product-form Neumann: Z = sum_{j=0}^{15} X^j (||X||^16 <= 1e-16)
  if (use_mfma) {
    for (int k = 0; k < 3; ++k) {
      mm64_mfma<false>(Xd, Xd, Xd, wv_i, wv_j, lr, lq, rowm, colm);
      mm64_mfma<true >(Pd, Xd, Pd, wv_i, wv_j, lr, lq, rowm, colm);
    }
  } else {
    for (int k = 0; k < 3; ++k) {
      mm64x2<false>(Xd, Xd, Xd, tr2, tc2);
      mm64x2<true >(Pd, Xd, Pd, tr2, tc2);
    }
  }

  // Pd = N1. Bb = step * N1 @ B  -> W[0]
  if (t < 64) {
    double bb = 0.0;
    for (int c = 0; c < 64; ++c) bb = fma(Pd[t * 65 + c], (double)Bin[c], bb);
    Wf[t] = (float)(bb * step);
  }
  __syncthreads();

  // Ab = 2*N1 - I (in place)
  for (int idx = t; idx < 4096; idx += 1024) {
    int i = idx >> 6, j = idx & 63;
    Pd[i * 65 + j] = 2.0 * Pd[i * 65 + j] - ((i == j) ? 1.0 : 0.0);
  }
  __syncthreads();

  // H[0] = C @ Ab
  if (t < 64) {
    double hh = 0.0;
    for (int c = 0; c < 64; ++c) hh = fma((double)Cin[c], Pd[c * 65 + t], hh);
    Hf[t] = (float)hh;
  }
  __syncthreads();

  // Log-doubling of W/H; P <- P*P shared with the M = Ab^128 chain.
  if (use_mfma) {
    for (int k = 0; k < 7; ++k) {
      const int n     = 1 << k;
      const int tpm   = (n + 15) >> 4;
      const int tiles = tpm << 2;
      if (tiles <= 8) {
        if (wave < 2 * tiles) {
          const bool isW = wave < tiles;
          const int  w   = isW ? wave : wave - tiles;
          wh_tile(Wf, Hf, Pd, Wf, Hf, n, isW, w >> 2, w & 3, lr, lq, rowm, colm);
        }
      } else {
        wh_tile(Wf, Hf, Pd, Wf, Hf, n, true,  wv_i, wv_j, lr, lq, rowm, colm);
        wh_tile(Wf, Hf, Pd, Wf, Hf, n, false, wv_i, wv_j, lr, lq, rowm, colm);
      }
      mm64_mfma<false>(Pd, Pd, Pd, wv_i, wv_j, lr, lq, rowm, colm);
    }
  } else {
    for (int k = 0; k < 7; ++k) {
      const int n = 1 << k;
      if (n <= 16) {
        if (t < (n << 6)) {
          int r = t >> 6, ii = t & 63;
          double aw = 0.0, ah = 0.0;
#pragma unroll 4
          for (int c = 0; c < 64; ++c) {
            aw = fma(Pd[ii * 65 + c], (double)Wf[r * 65 + c], aw);
            ah = fma((double)Hf[r * 65 + c], Pd[c * 65 + ii], ah);
          }
          Wf[(n + r) * 65 + ii] = (float)aw;
          Hf[(n + r) * 65 + ii] = (float)ah;
        }
      } else if (n == 32) {
        const int r  = t >> 5;
        const int i2 = (t & 31) << 1;
        double w0 = 0, w1 = 0, h0 = 0, h1 = 0;
#pragma unroll 4
        for (int c = 0; c < 64; ++c) {
          double wr = (double)Wf[r * 65 + c];
          w0 = fma(wr, Pd[(i2 + 0) * 65 + c], w0);
          w1 = fma(wr, Pd[(i2 + 1) * 65 + c], w1);
          double hr = (double)Hf[r * 65 + c];
          h0 = fma(hr, Pd[c * 65 + i2 + 0], h0);
          h1 = fma(hr, Pd[c * 65 + i2 + 1], h1);
        }
        Wf[(32 + r) * 65 + i2 + 0] = (float)w0;
        Wf[(32 + r) * 65 + i2 + 1] = (float)w1;
        Hf[(32 + r) * 65 + i2 + 0] = (float)h0;
        Hf[(32 + r) * 65 + i2 + 1] = (float)h1;
      } else {
        const int r2 = tr2, i2 = tc2;
        double w00 = 0, w01 = 0, w10 = 0, w11 = 0;
        double h00 = 0, h01 = 0, h10 = 0, h11 = 0;
#pragma unroll 4
        for (int c = 0; c < 64; ++c) {
          double wa = (double)Wf[(r2 + 0) * 65 + c];
          double wb = (double)Wf[(r2 + 1) * 65 + c];
          double p0 = Pd[(i2 + 0) * 65 + c];
          double p1 = Pd[(i2 + 1) * 65 + c];
          w00 = fma(wa, p0, w00); w01 = fma(wa, p1, w01);
          w10 = fma(wb, p0, w10); w11 = fma(wb, p1, w11);
          double ha = (double)Hf[(r2 + 0) * 65 + c];
          double hb = (double)Hf[(r2 + 1) * 65 + c];
          double q0 = Pd[c * 65 + i2 + 0];
          double q1 = Pd[c * 65 + i2 + 1];
          h00 = fma(ha, q0, h00); h01 = fma(ha, q1, h01);
          h10 = fma(hb, q0, h10); h11 = fma(hb, q1, h11);
        }
        Wf[(64 + r2 + 0) * 65 + i2 + 0] = (float)w00;
        Wf[(64 + r2 + 0) * 65 + i2 + 1] = (float)w01;
        Wf[(64 + r2 + 1) * 65 + i2 + 0] = (float)w10;
        Wf[(64 + r2 + 1) * 65 + i2 + 1] = (float)w11;
        Hf[(64 + r2 + 0) * 65 + i2 + 0] = (float)h00;
        Hf[(64 + r2 + 0) * 65 + i2 + 1] = (float)h01;
        Hf[(64 + r2 + 1) * 65 + i2 + 0] = (float)h10;
        Hf[(64 + r2 + 1) * 65 + i2 + 1] = (float)h11;
      }
      mm64x2<false>(Pd, Pd, Pd, tr2, tc2);
    }
  }

  // Pd = Ab^128 = M -> fp32 global (reads complete before the next squaring
  // overwrites Pd: each thread's LDS reads drain at the mm64-internal barrier)
  for (int idx = t; idx < 4096; idx += 1024)
    Mf[idx] = (float)Pd[(idx >> 6) * 65 + (idx & 63)];

  // One more squaring: Pd = Ab^256 = M^2 -> fp32 global
  if (use_mfma) mm64_mfma<false>(Pd, Pd, Pd, wv_i, wv_j, lr, lq, rowm, colm);
  else          mm64x2<false>(Pd, Pd, Pd, tr2, tc2);
  for (int idx = t; idx < 4096; idx += 1024)
    Mf[4096 + idx] = (float)Pd[(idx >> 6) * 65 + (idx & 63)];

  // K[r] = C . W[r]
  if (t < 128) {
    double s = 0.0;
    for (int c = 0; c < 64; ++c) s = fma((double)Cin[c], (double)Wf[t * 65 + c], s);
    Kf[t] = (float)s;
  }
  __syncthreads();

  // Wt[i][k] = bf16(W[127-k][i])  (64 x 128)
  for (int idx = t; idx < 8192; idx += 1024) {
    int i = idx >> 7, kk = idx & 127;
    Wtg[idx] = f2bf(Wf[(127 - kk) * 65 + i]);
  }

  // Gt[r][k] bf16, stride 192. Toeplitz part (k<128): K[r-k] + D*(k==r).
  const float Dval = Din[0];
  for (int idx = t; idx < 16384; idx += 1024) {
    int r = idx >> 7, kg = idx & 127;
    float v = (r >= kg) ? Kf[r - kg] : 0.f;
    if (kg == r) v += Dval;
    Gtg[r * 192 + kg] = f2bf(v);
  }
  // Cross-chunk part: Gt[r][128+i] = bf16(H[r][i]).
  for (int idx = t; idx < 8192; idx += 1024) {
    int r = idx >> 6, i = idx & 63;
    Gtg[r * 192 + 128 + i] = f2bf(Hf[r * 65 + i]);
  }
}

// ---------------------------------------------------------------------------
// Kernel B: chunk input vectors via bf16 MFMA.
//   b[rc][i] = sum_k u[rc][k] * Wt[i][k],  M=65536, N=64, K=128.
// ---------------------------------------------------------------------------
__global__ __launch_bounds__(256) void k_chunkvec(
    const float* __restrict__ u, const unsigned short* __restrict__ Wt,
    float* __restrict__ bout)
{
  __shared__ unsigned short Bs[64 * 136];
  __shared__ unsigned short As[128 * 40];
  const int t = threadIdx.x;
  const int rc0 = blockIdx.x << 7;
  const int w  = t >> 6;
  const int lane = t & 63;
  const int lr = lane & 15, lq = lane >> 4;

  {
    const unsigned* src = (const unsigned*)Wt;
    unsigned* dst = (unsigned*)Bs;
    for (int idx = t; idx < 4096; idx += 256) {
      int r = idx >> 6, c = idx & 63;
      dst[r * 68 + c] = src[idx];
    }
  }
  for (int it = t; it < 1024; it += 256) {
    int rcl = it >> 3, k4 = (it & 7) << 2;
    float4 v = *(const float4*)&u[((size_t)(rc0 + rcl) << 7) + k4];
    ushort4 s;
    s.x = f2bf(v.x); s.y = f2bf(v.y); s.z = f2bf(v.z); s.w = f2bf(v.w);
    *(ushort4*)&As[rcl * 40 + k4] = s;
  }
  __syncthreads();

  f32x4 acc[2][4];
#pragma unroll
  for (int i = 0; i < 2; ++i)
#pragma unroll
    for (int j = 0; j < 4; ++j) { acc[i][j][0] = 0.f; acc[i][j][1] = 0.f; acc[i][j][2] = 0.f; acc[i][j][3] = 0.f; }

  for (int sl = 0; sl < 4; ++sl) {
    bf16x8 av[2], bv[4];
#pragma unroll
    for (int ti = 0; ti < 2; ++ti)
      av[ti] = *(const bf16x8*)&As[(w * 32 + ti * 16 + lr) * 40 + lq * 8];
#pragma unroll
    for (int tj = 0; tj < 4; ++tj)
      bv[tj] = *(const bf16x8*)&Bs[(tj * 16 + lr) * 136 + sl * 32 + lq * 8];
#pragma unroll
    for (int ti = 0; ti < 2; ++ti)
#pragma unroll
      for (int tj = 0; tj < 4; ++tj)
        acc[ti][tj] = __builtin_amdgcn_mfma_f32_16x16x32_bf16(av[ti], bv[tj], acc[ti][tj], 0, 0, 0);
    if (sl < 3) {
      __syncthreads();
      for (int it = t; it < 1024; it += 256) {
        int rcl = it >> 3, k4 = (it & 7) << 2;
        float4 v = *(const float4*)&u[((size_t)(rc0 + rcl) << 7) + ((sl + 1) << 5) + k4];
        ushort4 s;
        s.x = f2bf(v.x); s.y = f2bf(v.y); s.z = f2bf(v.z); s.w = f2bf(v.w);
        *(ushort4*)&As[rcl * 40 + k4] = s;
      }
      __syncthreads();
    }
  }

#pragma unroll
  for (int ti = 0; ti < 2; ++ti)
#pragma unroll
    for (int tj = 0; tj < 4; ++tj)
#pragma unroll
      for (int r = 0; r < 4; ++r) {
        int row = rc0 + w * 32 + ti * 16 + lq * 4 + r;
        bout[((size_t)row << 6) + tj * 16 + lr] = acc[ti][tj][r];
      }
}

// ---------------------------------------------------------------------------
// Kernel C: depth-halved chunk-state scan. One block (256 thr) per row.
//   d_t = M b_{2t} + b_{2t+1}            (parallel, 4 waves)
//   X_{2t+2} = M^2 X_{2t} + d_t          (serial, 64 iters, wave 0,
//                                         x in regs, readlane broadcast)
//   X_{2t+1} = M X_{2t} + b_{2t}         (parallel fixup + stores)
// Serial critical path ~400 cyc/iter x 64 vs round-5's ~1065 x 128.
// ---------------------------------------------------------------------------
__global__ __launch_bounds__(256) void k_scan(
    const float* __restrict__ Mf,     // [0..4095]=M, [4096..8191]=M^2 (fp32)
    const float* __restrict__ bv, float* __restrict__ Xg)
{
  __shared__ float bs[128 * 64];   // 32 KB: b row
  __shared__ float ds[64 * 64];    // 16 KB: d_t
  __shared__ float xs[64 * 64];    // 16 KB: X_{2t}
  const int t = threadIdx.x, w = t >> 6, lane = t & 63;
  const float* br = bv + ((size_t)blockIdx.x << 13);
  float* Xr = Xg + ((size_t)blockIdx.x << 13);

  // stage b row (coalesced float4)
  for (int it = t; it < 2048; it += 256)
    ((float4*)bs)[it] = ((const float4*)br)[it];

  // per-lane M / M^2 rows (L2-hot: every block reads the same 32 KB)
  float Mr[64], M2r[64];
#pragma unroll
  for (int c4 = 0; c4 < 16; ++c4) {
    *(float4*)&Mr[c4 * 4]  = *(const float4*)&Mf[(lane << 6) + c4 * 4];
    *(float4*)&M2r[c4 * 4] = *(const float4*)&Mf[4096 + (lane << 6) + c4 * 4];
  }
  __syncthreads();

  // phase d: d_t = M b_{2t} + b_{2t+1}, t split over 4 waves
  for (int k = 0; k < 16; ++k) {
    const int tp = (w << 4) + k;
    float y0 = 0.f, y1 = 0.f, y2 = 0.f, y3 = 0.f;
#pragma unroll
    for (int c4 = 0; c4 < 16; ++c4) {
      float4 bb = *(const float4*)&bs[((tp << 1) << 6) + (c4 << 2)];  // broadcast
      y0 = fmaf(Mr[c4 * 4 + 0], bb.x, y0);
      y1 = fmaf(Mr[c4 * 4 + 1], bb.y, y1);
      y2 = fmaf(Mr[c4 * 4 + 2], bb.z, y2);
      y3 = fmaf(Mr[c4 * 4 + 3], bb.w, y3);
    }
    ds[(tp << 6) + lane] = ((y0 + y1) + (y2 + y3)) + bs[(((tp << 1) + 1) << 6) + lane];
  }
  __syncthreads();

  // serial phase (wave 0): 64 iters, x in registers, readlane broadcast
  if (w == 0) {
    float x = 0.f;
    float ecur = ds[lane];
    for (int u = 0; u < 64; ++u) {
      xs[(u << 6) + lane] = x;                      // X_{2u}
      float en = (u < 63) ? ds[((u + 1) << 6) + lane] : 0.f;
      const unsigned xb = __float_as_uint(x);
      float y0 = 0.f, y1 = 0.f, y2 = 0.f, y3 = 0.f;
#pragma unroll
      for (int c = 0; c < 64; c += 4) {
        y0 = fmaf(M2r[c + 0], __uint_as_float(__builtin_amdgcn_readlane(xb, c + 0)), y0);
        y1 = fmaf(M2r[c + 1], __uint_as_float(__builtin_amdgcn_readlane(xb, c + 1)), y1);
        y2 = fmaf(M2r[c + 2], __uint_as_float(__builtin_amdgcn_readlane(xb, c + 2)), y2);
        y3 = fmaf(M2r[c + 3], __uint_as_float(__builtin_amdgcn_readlane(xb, c + 3)), y3);
      }
      x = ((y0 + y1) + (y2 + y3)) + ecur;
      ecur = en;
    }
  }
  __syncthreads();

  // fixup + stores: X_{2t} = xs[t]; X_{2t+1} = M xs[t] + b_{2t}
  for (int k = 0; k < 16; ++k) {
    const int tp = (w << 4) + k;
    Xr[((tp << 1) << 6) + lane] = xs[(tp << 6) + lane];
    float y0 = 0.f, y1 = 0.f, y2 = 0.f, y3 = 0.f;
#pragma unroll
    for (int c4 = 0; c4 < 16; ++c4) {
      float4 xx = *(const float4*)&xs[(tp << 6) + (c4 << 2)];  // broadcast
      y0 = fmaf(Mr[c4 * 4 + 0], xx.x, y0);
      y1 = fmaf(Mr[c4 * 4 + 1], xx.y, y1);
      y2 = fmaf(Mr[c4 * 4 + 2], xx.z, y2);
      y3 = fmaf(Mr[c4 * 4 + 3], xx.w, y3);
    }
    Xr[(((tp << 1) + 1) << 6) + lane] =
        ((y0 + y1) + (y2 + y3)) + bs[((tp << 1) << 6) + lane];
  }
}

// ---------------------------------------------------------------------------
// Kernel D: main output GEMM via bf16 MFMA.
//   y[rc][r] = sum_{k<192} As[rc][k] * Gt[r][k]   (As = [u | X])
// ---------------------------------------------------------------------------
__global__ __launch_bounds__(256) void k_main(
    const float* __restrict__ u, const float* __restrict__ Xg,
    const unsigned short* __restrict__ Gt, float* __restrict__ out)
{
  __shared__ unsigned short Gs[128 * 200];
  __shared__ unsigned short As[128 * 40];
  const int t = threadIdx.x;
  const int rc0 = blockIdx.x << 7;
  const int w  = t >> 6;
  const int lane = t & 63;
  const int lr = lane & 15, lq = lane >> 4;

  {
    const unsigned* src = (const unsigned*)Gt;
    unsigned* dst = (unsigned*)Gs;
    for (int idx = t; idx < 12288; idx += 256) {
      int r = idx / 96, c = idx - r * 96;
      dst[r * 100 + c] = src[idx];
    }
  }
  for (int it = t; it < 1024; it += 256) {
    int rcl = it >> 3, k4 = (it & 7) << 2;
    float4 v = *(const float4*)&u[((size_t)(rc0 + rcl) << 7) + k4];
    ushort4 s;
    s.x = f2bf(v.x); s.y = f2bf(v.y); s.z = f2bf(v.z); s.w = f2bf(v.w);
    *(ushort4*)&As[rcl * 40 + k4] = s;
  }
  __syncthreads();

  f32x4 acc[2][8];
#pragma unroll
  for (int i = 0; i < 2; ++i)
#pragma unroll
    for (int j = 0; j < 8; ++j) { acc[i][j][0] = 0.f; acc[i][j][1] = 0.f; acc[i][j][2] = 0.f; acc[i][j][3] = 0.f; }

  for (int sl = 0; sl < 6; ++sl) {
    bf16x8 av[2], bv[8];
#pragma unroll
    for (int ti = 0; ti < 2; ++ti)
      av[ti] = *(const bf16x8*)&As[(w * 32 + ti * 16 + lr) * 40 + lq * 8];
#pragma unroll
    for (int tj = 0; tj < 8; ++tj)
      bv[tj] = *(const bf16x8*)&Gs[(tj * 16 + lr) * 200 + sl * 32 + lq * 8];
#pragma unroll
    for (int ti = 0; ti < 2; ++ti)
#pragma unroll
      for (int tj = 0; tj < 8; ++tj)
        acc[ti][tj] = __builtin_amdgcn_mfma_f32_16x16x32_bf16(av[ti], bv[tj], acc[ti][tj], 0, 0, 0);
    if (sl < 5) {
      __syncthreads();
      for (int it = t; it < 1024; it += 256) {
        int rcl = it >> 3, k4 = (it & 7) << 2;
        int kg = ((sl + 1) << 5) + k4;
        float4 v;
        if (kg < 128)
          v = *(const float4*)&u[((size_t)(rc0 + rcl) << 7) + kg];
        else
          v = *(const float4*)&Xg[((size_t)(rc0 + rcl) << 6) + (kg - 128)];
        ushort4 s;
        s.x = f2bf(v.x); s.y = f2bf(v.y); s.z = f2bf(v.z); s.w = f2bf(v.w);
        *(ushort4*)&As[rcl * 40 + k4] = s;
      }
      __syncthreads();
    }
  }

#pragma unroll
  for (int ti = 0; ti < 2; ++ti)
#pragma unroll
    for (int tj = 0; tj < 8; ++tj)
#pragma unroll
      for (int r = 0; r < 4; ++r) {
        int row = rc0 + w * 32 + ti * 16 + lq * 4 + r;
        out[((size_t)row << 7) + tj * 16 + lr] = acc[ti][tj][r];
      }
}

// ---------------------------------------------------------------------------
extern "C" void kernel_launch(void* const* d_in, const int* in_sizes, int n_in,
                              void* d_out, int out_size, void* d_ws, size_t ws_size,
                              hipStream_t stream) {
  (void)in_sizes; (void)n_in; (void)out_size; (void)ws_size;
  const float* u  = (const float*)d_in[0];
  const float* A  = (const float*)d_in[1];
  const float* Bv = (const float*)d_in[2];
  const float* Cv = (const float*)d_in[3];
  const float* Dv = (const float*)d_in[4];
  const float* ls = (const float*)d_in[5];
  float* out = (float*)d_out;
  float* ws  = (float*)d_ws;

  k_precomp<<<1, 1024, 0, stream>>>(A, Bv, Cv, Dv, ls, ws);
  k_chunkvec<<<512, 256, 0, stream>>>(u, (const unsigned short*)(ws + WS_W), ws + WS_BV);
  k_scan<<<512, 256, 0, stream>>>(ws + WS_MD, ws + WS_BV, ws + WS_X);
  k_main<<<512, 256, 0, stream>>>(u, ws + WS_X, (const unsigned short*)(ws + WS_G), out);
}

// Round 7
// 188.599 us; speedup vs baseline: 1.9235x; 1.1191x over previous
//
#include <hip/hip_runtime.h>
#include <cstddef>

typedef double f64x4 __attribute__((ext_vector_type(4)));
typedef float  f32x4 __attribute__((ext_vector_type(4)));
typedef short  bf16x8 __attribute__((ext_vector_type(8)));   // 8 bf16 = 4 VGPRs

// Problem constants: N=64 state dim, L=16384 seq, BATCH=512, chunk m=128.
static constexpr int RCN = 512 * 128;   // 65536 (row, chunk) pairs

// ws layout (float offsets). WS_W holds Wt bf16 (64x128 ushort); WS_G holds
// Gt bf16 (128x192 ushort). WS_MD holds M fp32 [0..4095] + M^2 fp32
// [4096..8191]. (BV/X regions no longer used: fused kernel keeps b and X
// on-chip.)
static constexpr size_t WS_W  = 0;
static constexpr size_t WS_G  = 8192;
static constexpr size_t WS_MD = 32768;
static constexpr size_t WS_BV = 40960;
static constexpr size_t WS_X  = WS_BV + (size_t)RCN * 64;

// fp32 -> bf16 round-to-nearest-even (finite inputs only)
__device__ __forceinline__ unsigned short f2bf(float f) {
  union { float f; unsigned u; } v; v.f = f;
  unsigned u = v.u + 0x7FFFu + ((v.u >> 16) & 1u);
  return (unsigned short)(u >> 16);
}

// ---------------------------------------------------------------------------
// f64 MFMA layout probe (verified working rounds 4-6). Pure-register.
// ---------------------------------------------------------------------------
__device__ __forceinline__ double probeE(int i, int k) {
  return (double)(((i * 3 + k * 5) & 7) - 3);
}
__device__ __forceinline__ double probeF(int k, int j) {
  return (double)(((k * 7 + j * 2) & 7) - 4);
}

__device__ __forceinline__ bool probe_mfma_layout(int lr, int lq, int rowm[4], int* colm_out)
{
  f64x4 z; z[0] = 0.0; z[1] = 0.0; z[2] = 0.0; z[3] = 0.0;
  f64x4 p1 = __builtin_amdgcn_mfma_f64_16x16x4f64((double)lr, 1.0, z, 0, 0, 0);
  f64x4 p2 = __builtin_amdgcn_mfma_f64_16x16x4f64(1.0, (double)lr, z, 0, 0, 0);
  bool okl = true;
#pragma unroll
  for (int r = 0; r < 4; ++r) {
    int rr = (int)(p1[r] * 0.25 + 0.5);
    okl = okl && (p1[r] == 4.0 * (double)rr) && rr >= 0 && rr < 16;
    rowm[r] = rr & 15;
    okl = okl && (p2[r] == p2[0]);
  }
  int cc = (int)(p2[0] * 0.25 + 0.5);
  okl = okl && (p2[0] == 4.0 * (double)cc) && cc >= 0 && cc < 16;
  *colm_out = cc & 15;
  f64x4 d = __builtin_amdgcn_mfma_f64_16x16x4f64(probeE(lr, lq), probeF(lq, lr), z, 0, 0, 0);
#pragma unroll
  for (int r = 0; r < 4; ++r) {
    double ref = 0.0;
#pragma unroll
    for (int k = 0; k < 4; ++k) ref += probeE(rowm[r], k) * probeF(k, cc & 15);
    okl = okl && (d[r] == ref);
  }
  return __all(okl) != 0;
}

// ---------------------------------------------------------------------------
// In-place 64x64x64 fp64 matmul in LDS via v_mfma_f64_16x16x4_f64.
// ---------------------------------------------------------------------------
template<bool ADD>
__device__ __forceinline__ void mm64_mfma(const double* A, const double* B, double* D,
                                          int wi, int wj, int lr, int lq,
                                          const int rowm[4], int colm)
{
  f64x4 acc;
  if (ADD) {
#pragma unroll
    for (int r = 0; r < 4; ++r)
      acc[r] = D[(wi * 16 + rowm[r]) * 65 + wj * 16 + colm];
  } else {
    acc[0] = 0.0; acc[1] = 0.0; acc[2] = 0.0; acc[3] = 0.0;
  }
#pragma unroll
  for (int kb = 0; kb < 16; ++kb) {
    double a = A[(wi * 16 + lr) * 65 + kb * 4 + lq];
    double b = B[(kb * 4 + lq) * 65 + wj * 16 + lr];
    acc = __builtin_amdgcn_mfma_f64_16x16x4f64(a, b, acc, 0, 0, 0);
  }
  __syncthreads();
#pragma unroll
  for (int r = 0; r < 4; ++r)
    D[(wi * 16 + rowm[r]) * 65 + wj * 16 + colm] = acc[r];
  __syncthreads();
}

// One 16x16 tile of the W/H log-doubling expansion (MFMA, probed maps).
__device__ __forceinline__ void wh_tile(const float* Wf, const float* Hf,
                                        const double* Pd, float* Wo, float* Ho,
                                        int n, bool isW, int wi, int wj,
                                        int lr, int lq, const int rowm[4], int colm)
{
  f64x4 acc;
  acc[0] = 0.0; acc[1] = 0.0; acc[2] = 0.0; acc[3] = 0.0;
#pragma unroll
  for (int kb = 0; kb < 16; ++kb) {
    double a, b;
    if (isW) {
      a = (double)Wf[(wi * 16 + lr) * 65 + kb * 4 + lq];
      b = Pd[(wj * 16 + lr) * 65 + kb * 4 + lq];     // P^T fragment
    } else {
      a = (double)Hf[(wi * 16 + lr) * 65 + kb * 4 + lq];
      b = Pd[(kb * 4 + lq) * 65 + wj * 16 + lr];     // P fragment
    }
    acc = __builtin_amdgcn_mfma_f64_16x16x4f64(a, b, acc, 0, 0, 0);
  }
#pragma unroll
  for (int r = 0; r < 4; ++r) {
    int drow = wi * 16 + rowm[r];
    if (drow < n) {
      if (isW) Wo[(n + drow) * 65 + wj * 16 + colm] = (float)acc[r];
      else     Ho[(n + drow) * 65 + wj * 16 + colm] = (float)acc[r];
    }
  }
}

// VALU fallback matmul (known-passing round-2 path).
template<bool ADD>
__device__ __forceinline__ void mm64x2(const double* A, const double* B, double* D,
                                       int tr2, int tc2)
{
  double a00 = 0, a01 = 0, a10 = 0, a11 = 0;
#pragma unroll 8
  for (int c = 0; c < 64; ++c) {
    double av0 = A[(tr2 + 0) * 65 + c];
    double av1 = A[(tr2 + 1) * 65 + c];
    double bv0 = B[c * 65 + tc2 + 0];
    double bv1 = B[c * 65 + tc2 + 1];
    a00 = fma(av0, bv0, a00); a01 = fma(av0, bv1, a01);
    a10 = fma(av1, bv0, a10); a11 = fma(av1, bv1, a11);
  }
  double o00, o01, o10, o11;
  if (ADD) {
    o00 = D[(tr2 + 0) * 65 + tc2 + 0]; o01 = D[(tr2 + 0) * 65 + tc2 + 1];
    o10 = D[(tr2 + 1) * 65 + tc2 + 0]; o11 = D[(tr2 + 1) * 65 + tc2 + 1];
  }
  __syncthreads();
  D[(tr2 + 0) * 65 + tc2 + 0] = ADD ? (o00 + a00) : a00;
  D[(tr2 + 0) * 65 + tc2 + 1] = ADD ? (o01 + a01) : a01;
  D[(tr2 + 1) * 65 + tc2 + 0] = ADD ? (o10 + a10) : a10;
  D[(tr2 + 1) * 65 + tc2 + 1] = ADD ? (o11 + a11) : a11;
  __syncthreads();
}

// ---------------------------------------------------------------------------
// Kernel A: discretize + build all weights (unchanged from round 6, passing).
// Emits: Wt bf16, Gt bf16, and M / M^2 fp32.
// ---------------------------------------------------------------------------
__global__ __launch_bounds__(1024) void k_precomp(
    const float* __restrict__ Ain, const float* __restrict__ Bin,
    const float* __restrict__ Cin, const float* __restrict__ Din,
    const float* __restrict__ LS, float* ws)
{
  __shared__ double Xd[64 * 65];
  __shared__ double Pd[64 * 65];
  __shared__ float  Wf[128 * 65];
  __shared__ float  Hf[128 * 65];
  __shared__ float  Kf[128];

  const int t    = threadIdx.x;
  const int wave = t >> 6;
  const int lane = t & 63;
  const int lr   = lane & 15;
  const int lq   = lane >> 4;
  const int wv_i = wave >> 2;
  const int wv_j = wave & 3;
  const int tr2  = (t >> 5) << 1;
  const int tc2  = (t & 31) << 1;

  int rowm[4]; int colm;
  const bool use_mfma = probe_mfma_layout(lr, lq, rowm, &colm);

  unsigned short* Wtg = (unsigned short*)(ws + WS_W);
  unsigned short* Gtg = (unsigned short*)(ws + WS_G);
  float* Mf = ws + WS_MD;   // M fp32 [0..4095], M^2 fp32 [4096..8191]

  const double step = exp((double)LS[0]);
  const double h = 0.5 * step;

  for (int idx = t; idx < 4096; idx += 1024) {
    int i = idx >> 6, j = idx & 63;
    double a = h * (double)Ain[idx];
    Xd[i * 65 + j] = a;
    Pd[i * 65 + j] = a + ((i == j) ? 1.0 : 0.0);
  }
  __syncthreads();

  // Product-form Neumann: Z = sum_{j=0}^{15} X^j (||X||^16 <= 1e-16)
  if (use_mfma) {
    for (int k = 0; k < 3; ++k) {
      mm64_mfma<false>(Xd, Xd, Xd, wv_i, wv_j, lr, lq, rowm, colm);
      mm64_mfma<true >(Pd, Xd, Pd, wv_i, wv_j, lr, lq, rowm, colm);
    }
  } else {
    for (int k = 0; k < 3; ++k) {
      mm64x2<false>(Xd, Xd, Xd, tr2, tc2);
      mm64x2<true >(Pd, Xd, Pd, tr2, tc2);
    }
  }

  // Pd = N1. Bb = step * N1 @ B  -> W[0]
  if (t < 64) {
    double bb = 0.0;
    for (int c = 0; c < 64; ++c) bb = fma(Pd[t * 65 + c], (double)Bin[c], bb);
    Wf[t] = (float)(bb * step);
  }
  __syncthreads();

  // Ab = 2*N1 - I (in place)
  for (int idx = t; idx < 4096; idx += 1024) {
    int i = idx >> 6, j = idx & 63;
    Pd[i * 65 + j] = 2.0 * Pd[i * 65 + j] - ((i == j) ? 1.0 : 0.0);
  }
  __syncthreads();

  // H[0] = C @ Ab
  if (t < 64) {
    double hh = 0.0;
    for (int c = 0; c < 64; ++c) hh = fma((double)Cin[c], Pd[c * 65 + t], hh);
    Hf[t] = (float)hh;
  }
  __syncthreads();

  // Log-doubling of W/H; P <- P*P shared with the M = Ab^128 chain.
  if (use_mfma) {
    for (int k = 0; k < 7; ++k) {
      const int n     = 1 << k;
      const int tpm   = (n + 15) >> 4;
      const int tiles = tpm << 2;
      if (tiles <= 8) {
        if (wave < 2 * tiles) {
          const bool isW = wave < tiles;
          const int  w   = isW ? wave : wave - tiles;
          wh_tile(Wf, Hf, Pd, Wf, Hf, n, isW, w >> 2, w & 3, lr, lq, rowm, colm);
        }
      } else {
        wh_tile(Wf, Hf, Pd, Wf, Hf, n, true,  wv_i, wv_j, lr, lq, rowm, colm);
        wh_tile(Wf, Hf, Pd, Wf, Hf, n, false, wv_i, wv_j, lr, lq, rowm, colm);
      }
      mm64_mfma<false>(Pd, Pd, Pd, wv_i, wv_j, lr, lq, rowm, colm);
    }
  } else {
    for (int k = 0; k < 7; ++k) {
      const int n = 1 << k;
      if (n <= 16) {
        if (t < (n << 6)) {
          int r = t >> 6, ii = t & 63;
          double aw = 0.0, ah = 0.0;
#pragma unroll 4
          for (int c = 0; c < 64; ++c) {
            aw = fma(Pd[ii * 65 + c], (double)Wf[r * 65 + c], aw);
            ah = fma((double)Hf[r * 65 + c], Pd[c * 65 + ii], ah);
          }
          Wf[(n + r) * 65 + ii] = (float)aw;
          Hf[(n + r) * 65 + ii] = (float)ah;
        }
      } else if (n == 32) {
        const int r  = t >> 5;
        const int i2 = (t & 31) << 1;
        double w0 = 0, w1 = 0, h0 = 0, h1 = 0;
#pragma unroll 4
        for (int c = 0; c < 64; ++c) {
          double wr = (double)Wf[r * 65 + c];
          w0 = fma(wr, Pd[(i2 + 0) * 65 + c], w0);
          w1 = fma(wr, Pd[(i2 + 1) * 65 + c], w1);
          double hr = (double)Hf[r * 65 + c];
          h0 = fma(hr, Pd[c * 65 + i2 + 0], h0);
          h1 = fma(hr, Pd[c * 65 + i2 + 1], h1);
        }
        Wf[(32 + r) * 65 + i2 + 0] = (float)w0;
        Wf[(32 + r) * 65 + i2 + 1] = (float)w1;
        Hf[(32 + r) * 65 + i2 + 0] = (float)h0;
        Hf[(32 + r) * 65 + i2 + 1] = (float)h1;
      } else {
        const int r2 = tr2, i2 = tc2;
        double w00 = 0, w01 = 0, w10 = 0, w11 = 0;
        double h00 = 0, h01 = 0, h10 = 0, h11 = 0;
#pragma unroll 4
        for (int c = 0; c < 64; ++c) {
          double wa = (double)Wf[(r2 + 0) * 65 + c];
          double wb = (double)Wf[(r2 + 1) * 65 + c];
          double p0 = Pd[(i2 + 0) * 65 + c];
          double p1 = Pd[(i2 + 1) * 65 + c];
          w00 = fma(wa, p0, w00); w01 = fma(wa, p1, w01);
          w10 = fma(wb, p0, w10); w11 = fma(wb, p1, w11);
          double ha = (double)Hf[(r2 + 0) * 65 + c];
          double hb = (double)Hf[(r2 + 1) * 65 + c];
          double q0 = Pd[c * 65 + i2 + 0];
          double q1 = Pd[c * 65 + i2 + 1];
          h00 = fma(ha, q0, h00); h01 = fma(ha, q1, h01);
          h10 = fma(hb, q0, h10); h11 = fma(hb, q1, h11);
        }
        Wf[(64 + r2 + 0) * 65 + i2 + 0] = (float)w00;
        Wf[(64 + r2 + 0) * 65 + i2 + 1] = (float)w01;
        Wf[(64 + r2 + 1) * 65 + i2 + 0] = (float)w10;
        Wf[(64 + r2 + 1) * 65 + i2 + 1] = (float)w11;
        Hf[(64 + r2 + 0) * 65 + i2 + 0] = (float)h00;
        Hf[(64 + r2 + 0) * 65 + i2 + 1] = (float)h01;
        Hf[(64 + r2 + 1) * 65 + i2 + 0] = (float)h10;
        Hf[(64 + r2 + 1) * 65 + i2 + 1] = (float)h11;
      }
      mm64x2<false>(Pd, Pd, Pd, tr2, tc2);
    }
  }

  // Pd = Ab^128 = M -> fp32 global
  for (int idx = t; idx < 4096; idx += 1024)
    Mf[idx] = (float)Pd[(idx >> 6) * 65 + (idx & 63)];

  // One more squaring: Pd = Ab^256 = M^2 -> fp32 global
  if (use_mfma) mm64_mfma<false>(Pd, Pd, Pd, wv_i, wv_j, lr, lq, rowm, colm);
  else          mm64x2<false>(Pd, Pd, Pd, tr2, tc2);
  for (int idx = t; idx < 4096; idx += 1024)
    Mf[4096 + idx] = (float)Pd[(idx >> 6) * 65 + (idx & 63)];

  // K[r] = C . W[r]
  if (t < 128) {
    double s = 0.0;
    for (int c = 0; c < 64; ++c) s = fma((double)Cin[c], (double)Wf[t * 65 + c], s);
    Kf[t] = (float)s;
  }
  __syncthreads();

  // Wt[i][k] = bf16(W[127-k][i])  (64 x 128)
  for (int idx = t; idx < 8192; idx += 1024) {
    int i = idx >> 7, kk = idx & 127;
    Wtg[idx] = f2bf(Wf[(127 - kk) * 65 + i]);
  }

  // Gt[r][k] bf16, stride 192. Toeplitz part (k<128): K[r-k] + D*(k==r).
  const float Dval = Din[0];
  for (int idx = t; idx < 16384; idx += 1024) {
    int r = idx >> 7, kg = idx & 127;
    float v = (r >= kg) ? Kf[r - kg] : 0.f;
    if (kg == r) v += Dval;
    Gtg[r * 192 + kg] = f2bf(v);
  }
  // Cross-chunk part: Gt[r][128+i] = bf16(H[r][i]).
  for (int idx = t; idx < 8192; idx += 1024) {
    int r = idx >> 6, i = idx & 63;
    Gtg[r * 192 + 128 + i] = f2bf(Hf[r * 65 + i]);
  }
}

// ---------------------------------------------------------------------------
// Kernel B': FUSED per-row pipeline. One block per batch row (512 blocks,
// 256 threads, 77 KB LDS -> 2 blocks/CU). Phases:
//   1. chunk GEMM  b[c][i] = sum_k u[c*128+k] * Wt[i][k]  (bf16 MFMA -> LDS)
//   2. depth-halved scan (d-phase / serial-64 / fixup), X emitted as bf16
//      in LDS (never hits HBM; b never hits HBM; u reread is L2-hot)
//   3. main GEMM  y[c][r] = sum_k [u|X][c][k] * Gt[r][k]  (bf16 MFMA -> out)
// LDS time-multiplex: bs/Wt/ds die before Gs staged over them; Xbf ushort
// [128][64] aliases xs fp32[64][64] EXACTLY row-for-row (rows 2t,2t+1 = xs
// row t; each wave's fixup tp-range is private -> no race).
// ---------------------------------------------------------------------------
__global__ __launch_bounds__(256, 2) void k_fused(
    const float* __restrict__ u, const unsigned short* __restrict__ Wt,
    const unsigned short* __restrict__ Gt, const float* __restrict__ Mf,
    float* __restrict__ out)
{
  __shared__ __align__(16) unsigned char Lds[78848];
  float*          bs  = (float*)(Lds);                    // [128][68] ph1-2
  unsigned short* WtS = (unsigned short*)(Lds + 34816);   // [64][136] ph1
  float*          dsb = (float*)(Lds + 34816);            // [64][68]  ph2
  unsigned short* Gs  = (unsigned short*)(Lds);           // [128][200] ph3
  unsigned short* As  = (unsigned short*)(Lds + 52224);   // [128][40] ph1,3
  float*          xs  = (float*)(Lds + 62464);            // [64][64]  ph2
  unsigned short* Xbf = (unsigned short*)(Lds + 62464);   // [128][64] ph2-3

  const int t    = threadIdx.x;
  const int w    = t >> 6;
  const int lane = t & 63;
  const int lr   = lane & 15, lq = lane >> 4;
  const int row  = blockIdx.x;
  const float* urow = u + ((size_t)row << 14);   // 128 chunks x 128
  float* orow = out + ((size_t)row << 14);

  auto stageA = [&](int k0) {
    for (int it = t; it < 1024; it += 256) {
      int rcl = it >> 3, k4 = (it & 7) << 2;
      float4 v = *(const float4*)&urow[(rcl << 7) + k0 + k4];
      ushort4 s;
      s.x = f2bf(v.x); s.y = f2bf(v.y); s.z = f2bf(v.z); s.w = f2bf(v.w);
      *(ushort4*)&As[rcl * 40 + k4] = s;
    }
  };

  // ---- phase 1: chunk GEMM -> bs (LDS) ----
  {
    const unsigned* srcW = (const unsigned*)Wt;
    unsigned* dstW = (unsigned*)WtS;
    for (int idx = t; idx < 4096; idx += 256) {
      int r = idx >> 6, c = idx & 63;
      dstW[r * 68 + c] = srcW[idx];
    }
    stageA(0);
    __syncthreads();

    f32x4 acc[2][4];
#pragma unroll
    for (int i = 0; i < 2; ++i)
#pragma unroll
      for (int j = 0; j < 4; ++j) { acc[i][j][0] = 0.f; acc[i][j][1] = 0.f; acc[i][j][2] = 0.f; acc[i][j][3] = 0.f; }

    for (int sl = 0; sl < 4; ++sl) {
      bf16x8 av[2], bv[4];
#pragma unroll
      for (int ti = 0; ti < 2; ++ti)
        av[ti] = *(const bf16x8*)&As[(w * 32 + ti * 16 + lr) * 40 + lq * 8];
#pragma unroll
      for (int tj = 0; tj < 4; ++tj)
        bv[tj] = *(const bf16x8*)&WtS[(tj * 16 + lr) * 136 + sl * 32 + lq * 8];
#pragma unroll
      for (int ti = 0; ti < 2; ++ti)
#pragma unroll
        for (int tj = 0; tj < 4; ++tj)
          acc[ti][tj] = __builtin_amdgcn_mfma_f32_16x16x32_bf16(av[ti], bv[tj], acc[ti][tj], 0, 0, 0);
      if (sl < 3) {
        __syncthreads();
        stageA((sl + 1) << 5);
        __syncthreads();
      }
    }
    // store acc -> bs (disjoint from As/WtS: no barrier needed before)
#pragma unroll
    for (int ti = 0; ti < 2; ++ti)
#pragma unroll
      for (int tj = 0; tj < 4; ++tj)
#pragma unroll
        for (int r = 0; r < 4; ++r)
          bs[(w * 32 + ti * 16 + lq * 4 + r) * 68 + tj * 16 + lr] = acc[ti][tj][r];
    __syncthreads();
  }

  // ---- phase 2: depth-halved scan ----
  {
    float Mr[64];
#pragma unroll
    for (int c4 = 0; c4 < 16; ++c4)
      *(float4*)&Mr[c4 * 4] = *(const float4*)&Mf[(lane << 6) + c4 * 4];

    // d-phase: d_t = M b_{2t} + b_{2t+1}
    for (int k = 0; k < 16; ++k) {
      const int tp = (w << 4) + k;
      float y0 = 0.f, y1 = 0.f, y2 = 0.f, y3 = 0.f;
#pragma unroll
      for (int c4 = 0; c4 < 16; ++c4) {
        float4 bb = *(const float4*)&bs[(tp << 1) * 68 + (c4 << 2)];  // broadcast
        y0 = fmaf(Mr[c4 * 4 + 0], bb.x, y0);
        y1 = fmaf(Mr[c4 * 4 + 1], bb.y, y1);
        y2 = fmaf(Mr[c4 * 4 + 2], bb.z, y2);
        y3 = fmaf(Mr[c4 * 4 + 3], bb.w, y3);
      }
      dsb[tp * 68 + lane] = ((y0 + y1) + (y2 + y3)) + bs[((tp << 1) + 1) * 68 + lane];
    }
    __syncthreads();

    // serial phase (wave 0): X_{2t+2} = M^2 X_{2t} + d_t, x in regs
    if (w == 0) {
      float M2r[64];
#pragma unroll
      for (int c4 = 0; c4 < 16; ++c4)
        *(float4*)&M2r[c4 * 4] = *(const float4*)&Mf[4096 + (lane << 6) + c4 * 4];
      float x = 0.f;
      float ecur = dsb[lane];
      for (int u2 = 0; u2 < 64; ++u2) {
        xs[(u2 << 6) + lane] = x;                     // X_{2u}
        float en = (u2 < 63) ? dsb[(u2 + 1) * 68 + lane] : 0.f;
        const unsigned xb = __float_as_uint(x);
        float y0 = 0.f, y1 = 0.f, y2 = 0.f, y3 = 0.f;
#pragma unroll
        for (int c = 0; c < 64; c += 4) {
          y0 = fmaf(M2r[c + 0], __uint_as_float(__builtin_amdgcn_readlane(xb, c + 0)), y0);
          y1 = fmaf(M2r[c + 1], __uint_as_float(__builtin_amdgcn_readlane(xb, c + 1)), y1);
          y2 = fmaf(M2r[c + 2], __uint_as_float(__builtin_amdgcn_readlane(xb, c + 2)), y2);
          y3 = fmaf(M2r[c + 3], __uint_as_float(__builtin_amdgcn_readlane(xb, c + 3)), y3);
        }
        x = ((y0 + y1) + (y2 + y3)) + ecur;
        ecur = en;
      }
    }
    __syncthreads();

    // fixup: Xbf[2t] = bf16(xs[t]); Xbf[2t+1] = bf16(M xs[t] + b_{2t}).
    // Xbf rows 2t,2t+1 alias xs row t exactly; each wave's tp range private.
    for (int k = 0; k < 16; ++k) {
      const int tp = (w << 4) + k;
      float y0 = 0.f, y1 = 0.f, y2 = 0.f, y3 = 0.f;
#pragma unroll
      for (int c4 = 0; c4 < 16; ++c4) {
        float4 xx = *(const float4*)&xs[(tp << 6) + (c4 << 2)];  // broadcast
        y0 = fmaf(Mr[c4 * 4 + 0], xx.x, y0);
        y1 = fmaf(Mr[c4 * 4 + 1], xx.y, y1);
        y2 = fmaf(Mr[c4 * 4 + 2], xx.z, y2);
        y3 = fmaf(Mr[c4 * 4 + 3], xx.w, y3);
      }
      float xeven = xs[(tp << 6) + lane];                 // read before alias-write
      float xodd  = ((y0 + y1) + (y2 + y3)) + bs[(tp << 1) * 68 + lane];
      Xbf[((tp << 1) + 0) * 64 + lane] = f2bf(xeven);
      Xbf[((tp << 1) + 1) * 64 + lane] = f2bf(xodd);
    }
    __syncthreads();
  }

  // ---- phase 3: main GEMM -> out ----
  {
    const unsigned* srcG = (const unsigned*)Gt;
    unsigned* dstG = (unsigned*)Gs;
    for (int idx = t; idx < 12288; idx += 256) {
      int r = idx / 96, c = idx - r * 96;
      dstG[r * 100 + c] = srcG[idx];
    }
    stageA(0);
    __syncthreads();

    f32x4 acc[2][8];
#pragma unroll
    for (int i = 0; i < 2; ++i)
#pragma unroll
      for (int j = 0; j < 8; ++j) { acc[i][j][0] = 0.f; acc[i][j][1] = 0.f; acc[i][j][2] = 0.f; acc[i][j][3] = 0.f; }

    for (int sl = 0; sl < 6; ++sl) {
      bf16x8 av[2], bv[8];
#pragma unroll
      for (int ti = 0; ti < 2; ++ti) {
        if (sl < 4)
          av[ti] = *(const bf16x8*)&As[(w * 32 + ti * 16 + lr) * 40 + lq * 8];
        else
          av[ti] = *(const bf16x8*)&Xbf[(w * 32 + ti * 16 + lr) * 64 + (sl - 4) * 32 + lq * 8];
      }
#pragma unroll
      for (int tj = 0; tj < 8; ++tj)
        bv[tj] = *(const bf16x8*)&Gs[(tj * 16 + lr) * 200 + sl * 32 + lq * 8];
#pragma unroll
      for (int ti = 0; ti < 2; ++ti)
#pragma unroll
        for (int tj = 0; tj < 8; ++tj)
          acc[ti][tj] = __builtin_amdgcn_mfma_f32_16x16x32_bf16(av[ti], bv[tj], acc[ti][tj], 0, 0, 0);
      if (sl < 3) {
        __syncthreads();
        stageA((sl + 1) << 5);   // u slices 1..3 (L2-hot reread)
        __syncthreads();
      }
    }

#pragma unroll
    for (int ti = 0; ti < 2; ++ti)
#pragma unroll
      for (int tj = 0; tj < 8; ++tj)
#pragma unroll
        for (int r = 0; r < 4; ++r) {
          int rcl = w * 32 + ti * 16 + lq * 4 + r;
          orow[((size_t)rcl << 7) + tj * 16 + lr] = acc[ti][tj][r];
        }
  }
}

// ---------------------------------------------------------------------------
extern "C" void kernel_launch(void* const* d_in, const int* in_sizes, int n_in,
                              void* d_out, int out_size, void* d_ws, size_t ws_size,
                              hipStream_t stream) {
  (void)in_sizes; (void)n_in; (void)out_size; (void)ws_size;
  const float* u  = (const float*)d_in[0];
  const float* A  = (const float*)d_in[1];
  const float* Bv = (const float*)d_in[2];
  const float* Cv = (const float*)d_in[3];
  const float* Dv = (const float*)d_in[4];
  const float* ls = (const float*)d_in[5];
  float* out = (float*)d_out;
  float* ws  = (float*)d_ws;

  k_precomp<<<1, 1024, 0, stream>>>(A, Bv, Cv, Dv, ls, ws);
  k_fused<<<512, 256, 0, stream>>>(u, (const unsigned short*)(ws + WS_W),
                                   (const unsigned short*)(ws + WS_G),
                                   ws + WS_MD, out);
}

// Round 8
// 186.547 us; speedup vs baseline: 1.9447x; 1.0110x over previous
//
#include <hip/hip_runtime.h>
#include <cstddef>

typedef double f64x4 __attribute__((ext_vector_type(4)));
typedef float  f32x4 __attribute__((ext_vector_type(4)));
typedef short  bf16x8 __attribute__((ext_vector_type(8)));   // 8 bf16 = 4 VGPRs

// Problem constants: N=64 state dim, L=16384 seq, BATCH=512, chunk m=128.
static constexpr int RCN = 512 * 128;   // 65536 (row, chunk) pairs

// ws layout (float offsets). WS_W holds Wt bf16 (64x128 ushort); WS_G holds
// Gt bf16 (128x192 ushort). WS_MD holds M fp32 [0..4095] + M^2 fp32
// [4096..8191], both in float4-chunked layout:
//   Mf[(c4<<8) + (row<<2) + j] = M[row][c4*4 + j]
// so "lane reads its own row" is a fully-coalesced float4 stream.
static constexpr size_t WS_W  = 0;
static constexpr size_t WS_G  = 8192;
static constexpr size_t WS_MD = 32768;

// fp32 -> bf16 round-to-nearest-even (finite inputs only)
__device__ __forceinline__ unsigned short f2bf(float f) {
  union { float f; unsigned u; } v; v.f = f;
  unsigned u = v.u + 0x7FFFu + ((v.u >> 16) & 1u);
  return (unsigned short)(u >> 16);
}

// ---------------------------------------------------------------------------
// f64 MFMA layout probe (verified working rounds 4-7). Pure-register.
// ---------------------------------------------------------------------------
__device__ __forceinline__ double probeE(int i, int k) {
  return (double)(((i * 3 + k * 5) & 7) - 3);
}
__device__ __forceinline__ double probeF(int k, int j) {
  return (double)(((k * 7 + j * 2) & 7) - 4);
}

__device__ __forceinline__ bool probe_mfma_layout(int lr, int lq, int rowm[4], int* colm_out)
{
  f64x4 z; z[0] = 0.0; z[1] = 0.0; z[2] = 0.0; z[3] = 0.0;
  f64x4 p1 = __builtin_amdgcn_mfma_f64_16x16x4f64((double)lr, 1.0, z, 0, 0, 0);
  f64x4 p2 = __builtin_amdgcn_mfma_f64_16x16x4f64(1.0, (double)lr, z, 0, 0, 0);
  bool okl = true;
#pragma unroll
  for (int r = 0; r < 4; ++r) {
    int rr = (int)(p1[r] * 0.25 + 0.5);
    okl = okl && (p1[r] == 4.0 * (double)rr) && rr >= 0 && rr < 16;
    rowm[r] = rr & 15;
    okl = okl && (p2[r] == p2[0]);
  }
  int cc = (int)(p2[0] * 0.25 + 0.5);
  okl = okl && (p2[0] == 4.0 * (double)cc) && cc >= 0 && cc < 16;
  *colm_out = cc & 15;
  f64x4 d = __builtin_amdgcn_mfma_f64_16x16x4f64(probeE(lr, lq), probeF(lq, lr), z, 0, 0, 0);
#pragma unroll
  for (int r = 0; r < 4; ++r) {
    double ref = 0.0;
#pragma unroll
    for (int k = 0; k < 4; ++k) ref += probeE(rowm[r], k) * probeF(k, cc & 15);
    okl = okl && (d[r] == ref);
  }
  return __all(okl) != 0;
}

// ---------------------------------------------------------------------------
// PING-PONG 64x64x64 fp64 matmuls: D = (Cin ? Cin : 0) + A*B. Reads and
// writes go to DIFFERENT buffers -> NO internal barriers (caller places ONE
// barrier per stage). This halves k_precomp's barrier count (the measured
// bottleneck: ~40 barriers x ~1-1.5K cyc drain with 16 waves).
// ---------------------------------------------------------------------------
__device__ __forceinline__ void mmPP_mfma(const double* A, const double* B,
                                          const double* Cin, double* D,
                                          int wi, int wj, int lr, int lq,
                                          const int rowm[4], int colm)
{
  f64x4 acc;
  if (Cin) {
#pragma unroll
    for (int r = 0; r < 4; ++r)
      acc[r] = Cin[(wi * 16 + rowm[r]) * 65 + wj * 16 + colm];
  } else {
    acc[0] = 0.0; acc[1] = 0.0; acc[2] = 0.0; acc[3] = 0.0;
  }
#pragma unroll
  for (int kb = 0; kb < 16; ++kb) {
    double a = A[(wi * 16 + lr) * 65 + kb * 4 + lq];
    double b = B[(kb * 4 + lq) * 65 + wj * 16 + lr];
    acc = __builtin_amdgcn_mfma_f64_16x16x4f64(a, b, acc, 0, 0, 0);
  }
#pragma unroll
  for (int r = 0; r < 4; ++r)
    D[(wi * 16 + rowm[r]) * 65 + wj * 16 + colm] = acc[r];
}

// VALU fallback, same buffer contract (2x2 tiles, 1024 threads).
__device__ __forceinline__ void mmPP_valu(const double* A, const double* B,
                                          const double* Cin, double* D,
                                          int tr2, int tc2)
{
  double a00, a01, a10, a11;
  if (Cin) {
    a00 = Cin[(tr2 + 0) * 65 + tc2 + 0]; a01 = Cin[(tr2 + 0) * 65 + tc2 + 1];
    a10 = Cin[(tr2 + 1) * 65 + tc2 + 0]; a11 = Cin[(tr2 + 1) * 65 + tc2 + 1];
  } else { a00 = a01 = a10 = a11 = 0.0; }
#pragma unroll 8
  for (int c = 0; c < 64; ++c) {
    double av0 = A[(tr2 + 0) * 65 + c];
    double av1 = A[(tr2 + 1) * 65 + c];
    double bv0 = B[c * 65 + tc2 + 0];
    double bv1 = B[c * 65 + tc2 + 1];
    a00 = fma(av0, bv0, a00); a01 = fma(av0, bv1, a01);
    a10 = fma(av1, bv0, a10); a11 = fma(av1, bv1, a11);
  }
  D[(tr2 + 0) * 65 + tc2 + 0] = a00;
  D[(tr2 + 0) * 65 + tc2 + 1] = a01;
  D[(tr2 + 1) * 65 + tc2 + 0] = a10;
  D[(tr2 + 1) * 65 + tc2 + 1] = a11;
}

// One 16x16 tile of the W/H log-doubling expansion (MFMA, probed maps).
// Writes rows [n,2n) -- disjoint from all stage reads; no internal barrier.
__device__ __forceinline__ void wh_tile(const float* Wf, const float* Hf,
                                        const double* Pd, float* Wo, float* Ho,
                                        int n, bool isW, int wi, int wj,
                                        int lr, int lq, const int rowm[4], int colm)
{
  f64x4 acc;
  acc[0] = 0.0; acc[1] = 0.0; acc[2] = 0.0; acc[3] = 0.0;
#pragma unroll
  for (int kb = 0; kb < 16; ++kb) {
    double a, b;
    if (isW) {
      a = (double)Wf[(wi * 16 + lr) * 65 + kb * 4 + lq];
      b = Pd[(wj * 16 + lr) * 65 + kb * 4 + lq];     // P^T fragment
    } else {
      a = (double)Hf[(wi * 16 + lr) * 65 + kb * 4 + lq];
      b = Pd[(kb * 4 + lq) * 65 + wj * 16 + lr];     // P fragment
    }
    acc = __builtin_amdgcn_mfma_f64_16x16x4f64(a, b, acc, 0, 0, 0);
  }
#pragma unroll
  for (int r = 0; r < 4; ++r) {
    int drow = wi * 16 + rowm[r];
    if (drow < n) {
      if (isW) Wo[(n + drow) * 65 + wj * 16 + colm] = (float)acc[r];
      else     Ho[(n + drow) * 65 + wj * 16 + colm] = (float)acc[r];
    }
  }
}

// ---------------------------------------------------------------------------
// Kernel A: discretize + build all weights. 1 block x 1024 threads (16 waves).
// Ping-pong buffer flow (ONE barrier per matmul stage):
//   SB0/SB1: X ping-pong during Neumann, then become Wf/Hf (fp32).
//   SB2/SB3: Z/P ping-pong for Neumann, Ab, and the squaring chain.
// Numerics identical to round 6/7 (fp64 Neumann, fp64 chain, fp32 W/H store).
// ---------------------------------------------------------------------------
__global__ __launch_bounds__(1024) void k_precomp(
    const float* __restrict__ Ain, const float* __restrict__ Bin,
    const float* __restrict__ Cin, const float* __restrict__ Din,
    const float* __restrict__ LS, float* ws)
{
  __shared__ double SB0[64 * 65];
  __shared__ double SB1[64 * 65];
  __shared__ double SB2[64 * 65];
  __shared__ double SB3[64 * 65];
  __shared__ float  Kf[128];
  float* Wf = (float*)SB0;   // 128x65 fp32 == 64x65 fp64 bytes
  float* Hf = (float*)SB1;

  const int t    = threadIdx.x;
  const int wave = t >> 6;
  const int lane = t & 63;
  const int lr   = lane & 15;
  const int lq   = lane >> 4;
  const int wv_i = wave >> 2;
  const int wv_j = wave & 3;
  const int tr2  = (t >> 5) << 1;
  const int tc2  = (t & 31) << 1;

  int rowm[4]; int colm;
  const bool use_mfma = probe_mfma_layout(lr, lq, rowm, &colm);

  unsigned short* Wtg = (unsigned short*)(ws + WS_W);
  unsigned short* Gtg = (unsigned short*)(ws + WS_G);
  float* Mf = ws + WS_MD;

  const double step = exp((double)LS[0]);
  const double h = 0.5 * step;

  // X = h*A -> SB0 ; Z = I + X -> SB2
  for (int idx = t; idx < 4096; idx += 1024) {
    int i = idx >> 6, j = idx & 63;
    double a = h * (double)Ain[idx];
    SB0[i * 65 + j] = a;
    SB2[i * 65 + j] = a + ((i == j) ? 1.0 : 0.0);
  }
  __syncthreads();

  // Product-form Neumann: Z <- Z + Z*X^2, X <- X^2, k=0..2
  // => Z = sum_{j=0}^{15} X^j ; truncation ||X||^16 <= 1e-16.
  {
    double *Xc = SB0, *Xn = SB1, *Zc = SB2, *Zn = SB3;
    for (int k = 0; k < 3; ++k) {
      if (use_mfma) mmPP_mfma(Xc, Xc, nullptr, Xn, wv_i, wv_j, lr, lq, rowm, colm);
      else          mmPP_valu(Xc, Xc, nullptr, Xn, tr2, tc2);
      __syncthreads();
      if (use_mfma) mmPP_mfma(Zc, Xn, Zc, Zn, wv_i, wv_j, lr, lq, rowm, colm);
      else          mmPP_valu(Zc, Xn, Zc, Zn, tr2, tc2);
      __syncthreads();
      double* tp_;
      tp_ = Xc; Xc = Xn; Xn = tp_;
      tp_ = Zc; Zc = Zn; Zn = tp_;
    }
    // N1 ends in SB3 (k=0 -> SB3, k=1 -> SB2, k=2 -> SB3). X buffers dead.
  }

  // Combined pass (both read-only on SB3 = N1):
  //   Bb = step * N1 @ B -> W[0] (Wf = dead SB0)
  //   Ab = 2*N1 - I -> SB2 (dead Z buffer)
  if (t < 64) {
    double bb = 0.0;
    for (int c = 0; c < 64; ++c) bb = fma(SB3[t * 65 + c], (double)Bin[c], bb);
    Wf[t] = (float)(bb * step);
  }
  for (int idx = t; idx < 4096; idx += 1024) {
    int i = idx >> 6, j = idx & 63;
    SB2[i * 65 + j] = 2.0 * SB3[i * 65 + j] - ((i == j) ? 1.0 : 0.0);
  }
  __syncthreads();

  // H[0] = C @ Ab (reads SB2 cols; Hf = dead SB1)
  if (t < 64) {
    double hh = 0.0;
    for (int c = 0; c < 64; ++c) hh = fma((double)Cin[c], SB2[c * 65 + t], hh);
    Hf[t] = (float)hh;
  }
  __syncthreads();

  // Log-doubling: P = Ab^n (n = 2^k) ping-pongs SB2<->SB3.
  //   W[n+r][i] = sum_c W[r][c] * P[i][c]
  //   H[n+r][i] = sum_c H[r][c] * P[c][i]
  // W/H writes (rows >= n) and P^2 writes (Pn) are disjoint from ALL stage
  // reads -> exactly ONE barrier per stage.
  double* Pc = SB2;
  double* Pn = SB3;
  for (int k = 0; k < 7; ++k) {
    const int n = 1 << k;
    if (use_mfma) {
      const int tpm   = (n + 15) >> 4;
      const int tiles = tpm << 2;
      if (tiles <= 8) {
        if (wave < 2 * tiles) {
          const bool isW = wave < tiles;
          const int  wq  = isW ? wave : wave - tiles;
          wh_tile(Wf, Hf, Pc, Wf, Hf, n, isW, wq >> 2, wq & 3, lr, lq, rowm, colm);
        }
      } else {
        wh_tile(Wf, Hf, Pc, Wf, Hf, n, true,  wv_i, wv_j, lr, lq, rowm, colm);
        wh_tile(Wf, Hf, Pc, Wf, Hf, n, false, wv_i, wv_j, lr, lq, rowm, colm);
      }
      mmPP_mfma(Pc, Pc, nullptr, Pn, wv_i, wv_j, lr, lq, rowm, colm);
    } else {
      for (int o = t; o < (n << 6); o += 1024) {
        int r = o >> 6, ii = o & 63;
        double aw = 0.0, ah = 0.0;
#pragma unroll 4
        for (int c = 0; c < 64; ++c) {
          aw = fma(Pc[ii * 65 + c], (double)Wf[r * 65 + c], aw);
          ah = fma((double)Hf[r * 65 + c], Pc[c * 65 + ii], ah);
        }
        Wf[(n + r) * 65 + ii] = (float)aw;
        Hf[(n + r) * 65 + ii] = (float)ah;
      }
      mmPP_valu(Pc, Pc, nullptr, Pn, tr2, tc2);
    }
    __syncthreads();
    double* tp_ = Pc; Pc = Pn; Pn = tp_;
  }
  // Pc = Ab^128 = M (7 stages: ends in SB3).

  // Export M (float4-chunked layout for coalesced per-lane row reads).
  for (int idx = t; idx < 4096; idx += 1024) {
    int row = idx >> 6, col = idx & 63;
    Mf[((col >> 2) << 8) + (row << 2) + (col & 3)] = (float)Pc[row * 65 + col];
  }
  // M^2 -> Pn (export reads Pc only; mm writes Pn only -> no barrier needed).
  if (use_mfma) mmPP_mfma(Pc, Pc, nullptr, Pn, wv_i, wv_j, lr, lq, rowm, colm);
  else          mmPP_valu(Pc, Pc, nullptr, Pn, tr2, tc2);
  __syncthreads();
  for (int idx = t; idx < 4096; idx += 1024) {
    int row = idx >> 6, col = idx & 63;
    Mf[4096 + ((col >> 2) << 8) + (row << 2) + (col & 3)] = (float)Pn[row * 65 + col];
  }

  // K[r] = C . W[r]
  if (t < 128) {
    double s = 0.0;
    for (int c = 0; c < 64; ++c) s = fma((double)Cin[c], (double)Wf[t * 65 + c], s);
    Kf[t] = (float)s;
  }
  __syncthreads();

  // Wt[i][k] = bf16(W[127-k][i])  (64 x 128)
  for (int idx = t; idx < 8192; idx += 1024) {
    int i = idx >> 7, kk = idx & 127;
    Wtg[idx] = f2bf(Wf[(127 - kk) * 65 + i]);
  }
  // Gt[r][k] bf16, stride 192. Toeplitz part (k<128): K[r-k] + D*(k==r).
  const float Dval = Din[0];
  for (int idx = t; idx < 16384; idx += 1024) {
    int r = idx >> 7, kg = idx & 127;
    float v = (r >= kg) ? Kf[r - kg] : 0.f;
    if (kg == r) v += Dval;
    Gtg[r * 192 + kg] = f2bf(v);
  }
  // Cross-chunk part: Gt[r][128+i] = bf16(H[r][i]).
  for (int idx = t; idx < 8192; idx += 1024) {
    int r = idx >> 6, i = idx & 63;
    Gtg[r * 192 + 128 + i] = f2bf(Hf[r * 65 + i]);
  }
}

// ---------------------------------------------------------------------------
// Kernel B': FUSED per-row pipeline (as round 7) with 3 latency fixes:
//   - Mr (M rows) loaded at kernel top from the coalesced chunked layout
//     (was a 64-way-split divergent load on the phase-2 critical path)
//   - phase-3's first u slice pre-staged during phase 2 (As dead there)
//   - M2r read from the coalesced layout
// ---------------------------------------------------------------------------
__global__ __launch_bounds__(256, 2) void k_fused(
    const float* __restrict__ u, const unsigned short* __restrict__ Wt,
    const unsigned short* __restrict__ Gt, const float* __restrict__ Mf,
    float* __restrict__ out)
{
  __shared__ __align__(16) unsigned char Lds[78848];
  float*          bs  = (float*)(Lds);                    // [128][68] ph1-2
  unsigned short* WtS = (unsigned short*)(Lds + 34816);   // [64][136] ph1
  float*          dsb = (float*)(Lds + 34816);            // [64][68]  ph2
  unsigned short* Gs  = (unsigned short*)(Lds);           // [128][200] ph3
  unsigned short* As  = (unsigned short*)(Lds + 52224);   // [128][40] ph1,3
  float*          xs  = (float*)(Lds + 62464);            // [64][64]  ph2
  unsigned short* Xbf = (unsigned short*)(Lds + 62464);   // [128][64] ph2-3

  const int t    = threadIdx.x;
  const int w    = t >> 6;
  const int lane = t & 63;
  const int lr   = lane & 15, lq = lane >> 4;
  const int row  = blockIdx.x;
  const float* urow = u + ((size_t)row << 14);   // 128 chunks x 128
  float* orow = out + ((size_t)row << 14);

  // Hoisted M row load (coalesced; latency hides under phase 1).
  float Mr[64];
#pragma unroll
  for (int c4 = 0; c4 < 16; ++c4)
    *(float4*)&Mr[c4 * 4] = *(const float4*)&Mf[(c4 << 8) + (lane << 2)];

  auto stageA = [&](int k0) {
    for (int it = t; it < 1024; it += 256) {
      int rcl = it >> 3, k4 = (it & 7) << 2;
      float4 v = *(const float4*)&urow[(rcl << 7) + k0 + k4];
      ushort4 s;
      s.x = f2bf(v.x); s.y = f2bf(v.y); s.z = f2bf(v.z); s.w = f2bf(v.w);
      *(ushort4*)&As[rcl * 40 + k4] = s;
    }
  };

  // ---- phase 1: chunk GEMM -> bs (LDS) ----
  {
    const unsigned* srcW = (const unsigned*)Wt;
    unsigned* dstW = (unsigned*)WtS;
    for (int idx = t; idx < 4096; idx += 256) {
      int r = idx >> 6, c = idx & 63;
      dstW[r * 68 + c] = srcW[idx];
    }
    stageA(0);
    __syncthreads();

    f32x4 acc[2][4];
#pragma unroll
    for (int i = 0; i < 2; ++i)
#pragma unroll
      for (int j = 0; j < 4; ++j) { acc[i][j][0] = 0.f; acc[i][j][1] = 0.f; acc[i][j][2] = 0.f; acc[i][j][3] = 0.f; }

    for (int sl = 0; sl < 4; ++sl) {
      bf16x8 av[2], bv[4];
#pragma unroll
      for (int ti = 0; ti < 2; ++ti)
        av[ti] = *(const bf16x8*)&As[(w * 32 + ti * 16 + lr) * 40 + lq * 8];
#pragma unroll
      for (int tj = 0; tj < 4; ++tj)
        bv[tj] = *(const bf16x8*)&WtS[(tj * 16 + lr) * 136 + sl * 32 + lq * 8];
#pragma unroll
      for (int ti = 0; ti < 2; ++ti)
#pragma unroll
        for (int tj = 0; tj < 4; ++tj)
          acc[ti][tj] = __builtin_amdgcn_mfma_f32_16x16x32_bf16(av[ti], bv[tj], acc[ti][tj], 0, 0, 0);
      if (sl < 3) {
        __syncthreads();
        stageA((sl + 1) << 5);
        __syncthreads();
      }
    }
#pragma unroll
    for (int ti = 0; ti < 2; ++ti)
#pragma unroll
      for (int tj = 0; tj < 4; ++tj)
#pragma unroll
        for (int r = 0; r < 4; ++r)
          bs[(w * 32 + ti * 16 + lq * 4 + r) * 68 + tj * 16 + lr] = acc[ti][tj][r];
    __syncthreads();
  }

  // ---- phase 2: depth-halved scan ----
  {
    // Pre-stage phase-3's first u slice (As is dead in phase 2; global-load
    // latency overlaps the whole scan; ordered by the phase-2 exit barrier).
    stageA(0);

    // d-phase: d_t = M b_{2t} + b_{2t+1}
    for (int k = 0; k < 16; ++k) {
      const int tp = (w << 4) + k;
      float y0 = 0.f, y1 = 0.f, y2 = 0.f, y3 = 0.f;
#pragma unroll
      for (int c4 = 0; c4 < 16; ++c4) {
        float4 bb = *(const float4*)&bs[(tp << 1) * 68 + (c4 << 2)];  // broadcast
        y0 = fmaf(Mr[c4 * 4 + 0], bb.x, y0);
        y1 = fmaf(Mr[c4 * 4 + 1], bb.y, y1);
        y2 = fmaf(Mr[c4 * 4 + 2], bb.z, y2);
        y3 = fmaf(Mr[c4 * 4 + 3], bb.w, y3);
      }
      dsb[tp * 68 + lane] = ((y0 + y1) + (y2 + y3)) + bs[((tp << 1) + 1) * 68 + lane];
    }
    __syncthreads();

    // serial phase (wave 0): X_{2t+2} = M^2 X_{2t} + d_t, x in regs
    if (w == 0) {
      float M2r[64];
#pragma unroll
      for (int c4 = 0; c4 < 16; ++c4)
        *(float4*)&M2r[c4 * 4] = *(const float4*)&Mf[4096 + (c4 << 8) + (lane << 2)];
      float x = 0.f;
      float ecur = dsb[lane];
      for (int u2 = 0; u2 < 64; ++u2) {
        xs[(u2 << 6) + lane] = x;                     // X_{2u}
        float en = (u2 < 63) ? dsb[(u2 + 1) * 68 + lane] : 0.f;
        const unsigned xb = __float_as_uint(x);
        float y0 = 0.f, y1 = 0.f, y2 = 0.f, y3 = 0.f;
#pragma unroll
        for (int c = 0; c < 64; c += 4) {
          y0 = fmaf(M2r[c + 0], __uint_as_float(__builtin_amdgcn_readlane(xb, c + 0)), y0);
          y1 = fmaf(M2r[c + 1], __uint_as_float(__builtin_amdgcn_readlane(xb, c + 1)), y1);
          y2 = fmaf(M2r[c + 2], __uint_as_float(__builtin_amdgcn_readlane(xb, c + 2)), y2);
          y3 = fmaf(M2r[c + 3], __uint_as_float(__builtin_amdgcn_readlane(xb, c + 3)), y3);
        }
        x = ((y0 + y1) + (y2 + y3)) + ecur;
        ecur = en;
      }
    }
    __syncthreads();

    // fixup: Xbf[2t] = bf16(xs[t]); Xbf[2t+1] = bf16(M xs[t] + b_{2t}).
    // Xbf rows 2t,2t+1 alias xs row t exactly; each wave's tp range private.
    for (int k = 0; k < 16; ++k) {
      const int tp = (w << 4) + k;
      float y0 = 0.f, y1 = 0.f, y2 = 0.f, y3 = 0.f;
#pragma unroll
      for (int c4 = 0; c4 < 16; ++c4) {
        float4 xx = *(const float4*)&xs[(tp << 6) + (c4 << 2)];  // broadcast
        y0 = fmaf(Mr[c4 * 4 + 0], xx.x, y0);
        y1 = fmaf(Mr[c4 * 4 + 1], xx.y, y1);
        y2 = fmaf(Mr[c4 * 4 + 2], xx.z, y2);
        y3 = fmaf(Mr[c4 * 4 + 3], xx.w, y3);
      }
      float xeven = xs[(tp << 6) + lane];                 // read before alias-write
      float xodd  = ((y0 + y1) + (y2 + y3)) + bs[(tp << 1) * 68 + lane];
      Xbf[((tp << 1) + 0) * 64 + lane] = f2bf(xeven);
      Xbf[((tp << 1) + 1) * 64 + lane] = f2bf(xodd);
    }
    __syncthreads();
  }

  // ---- phase 3: main GEMM -> out ----
  {
    const unsigned* srcG = (const unsigned*)Gt;
    unsigned* dstG = (unsigned*)Gs;
    for (int idx = t; idx < 12288; idx += 256) {
      int r = idx / 96, c = idx - r * 96;
      dstG[r * 100 + c] = srcG[idx];
    }
    // As slice 0 already staged during phase 2.
    __syncthreads();

    f32x4 acc[2][8];
#pragma unroll
    for (int i = 0; i < 2; ++i)
#pragma unroll
      for (int j = 0; j < 8; ++j) { acc[i][j][0] = 0.f; acc[i][j][1] = 0.f; acc[i][j][2] = 0.f; acc[i][j][3] = 0.f; }

    for (int sl = 0; sl < 6; ++sl) {
      bf16x8 av[2], bv[8];
#pragma unroll
      for (int ti = 0; ti < 2; ++ti) {
        if (sl < 4)
          av[ti] = *(const bf16x8*)&As[(w * 32 + ti * 16 + lr) * 40 + lq * 8];
        else
          av[ti] = *(const bf16x8*)&Xbf[(w * 32 + ti * 16 + lr) * 64 + (sl - 4) * 32 + lq * 8];
      }
#pragma unroll
      for (int tj = 0; tj < 8; ++tj)
        bv[tj] = *(const bf16x8*)&Gs[(tj * 16 + lr) * 200 + sl * 32 + lq * 8];
#pragma unroll
      for (int ti = 0; ti < 2; ++ti)
#pragma unroll
        for (int tj = 0; tj < 8; ++tj)
          acc[ti][tj] = __builtin_amdgcn_mfma_f32_16x16x32_bf16(av[ti], bv[tj], acc[ti][tj], 0, 0, 0);
      if (sl < 3) {
        __syncthreads();
        stageA((sl + 1) << 5);   // u slices 1..3 (L2-hot reread)
        __syncthreads();
      }
    }

#pragma unroll
    for (int ti = 0; ti < 2; ++ti)
#pragma unroll
      for (int tj = 0; tj < 8; ++tj)
#pragma unroll
        for (int r = 0; r < 4; ++r) {
          int rcl = w * 32 + ti * 16 + lq * 4 + r;
          orow[((size_t)rcl << 7) + tj * 16 + lr] = acc[ti][tj][r];
        }
  }
}

// ---------------------------------------------------------------------------
extern "C" void kernel_launch(void* const* d_in, const int* in_sizes, int n_in,
                              void* d_out, int out_size, void* d_ws, size_t ws_size,
                              hipStream_t stream) {
  (void)in_sizes; (void)n_in; (void)out_size; (void)ws_size;
  const float* u  = (const float*)d_in[0];
  const float* A  = (const float*)d_in[1];
  const float* Bv = (const float*)d_in[2];
  const float* Cv = (const float*)d_in[3];
  const float* Dv = (const float*)d_in[4];
  const float* ls = (const float*)d_in[5];
  float* out = (float*)d_out;
  float* ws  = (float*)d_ws;

  k_precomp<<<1, 1024, 0, stream>>>(A, Bv, Cv, Dv, ls, ws);
  k_fused<<<512, 256, 0, stream>>>(u, (const unsigned short*)(ws + WS_W),
                                   (const unsigned short*)(ws + WS_G),
                                   ws + WS_MD, out);
}

// Round 9
// 178.617 us; speedup vs baseline: 2.0310x; 1.0444x over previous
//
#include <hip/hip_runtime.h>
#include <cstddef>

typedef double f64x4 __attribute__((ext_vector_type(4)));
typedef float  f32x4 __attribute__((ext_vector_type(4)));
typedef short  bf16x8 __attribute__((ext_vector_type(8)));   // 8 bf16 = 4 VGPRs

// Problem constants: N=64 state dim, L=16384 seq, BATCH=512, chunk m=128.
static constexpr int RCN = 512 * 128;   // 65536 (row, chunk) pairs

// ws layout (float offsets). WS_W holds Wt bf16 (64x128 ushort); WS_G holds
// Gt bf16 (128x192 ushort). WS_MD holds M fp32 [0..4095] + M^2 fp32
// [4096..8191], float4-chunked: Mf[(c4<<8)+(row<<2)+j] = M[row][c4*4+j].
static constexpr size_t WS_W  = 0;
static constexpr size_t WS_G  = 8192;
static constexpr size_t WS_MD = 32768;

// fp32 -> bf16 round-to-nearest-even (finite inputs only)
__device__ __forceinline__ unsigned short f2bf(float f) {
  union { float f; unsigned u; } v; v.f = f;
  unsigned u = v.u + 0x7FFFu + ((v.u >> 16) & 1u);
  return (unsigned short)(u >> 16);
}

// ---------------------------------------------------------------------------
// f64 MFMA layout probe (verified working rounds 4-8). Pure-register.
// ---------------------------------------------------------------------------
__device__ __forceinline__ double probeE(int i, int k) {
  return (double)(((i * 3 + k * 5) & 7) - 3);
}
__device__ __forceinline__ double probeF(int k, int j) {
  return (double)(((k * 7 + j * 2) & 7) - 4);
}

__device__ __forceinline__ bool probe_mfma_layout(int lr, int lq, int rowm[4], int* colm_out)
{
  f64x4 z; z[0] = 0.0; z[1] = 0.0; z[2] = 0.0; z[3] = 0.0;
  f64x4 p1 = __builtin_amdgcn_mfma_f64_16x16x4f64((double)lr, 1.0, z, 0, 0, 0);
  f64x4 p2 = __builtin_amdgcn_mfma_f64_16x16x4f64(1.0, (double)lr, z, 0, 0, 0);
  bool okl = true;
#pragma unroll
  for (int r = 0; r < 4; ++r) {
    int rr = (int)(p1[r] * 0.25 + 0.5);
    okl = okl && (p1[r] == 4.0 * (double)rr) && rr >= 0 && rr < 16;
    rowm[r] = rr & 15;
    okl = okl && (p2[r] == p2[0]);
  }
  int cc = (int)(p2[0] * 0.25 + 0.5);
  okl = okl && (p2[0] == 4.0 * (double)cc) && cc >= 0 && cc < 16;
  *colm_out = cc & 15;
  f64x4 d = __builtin_amdgcn_mfma_f64_16x16x4f64(probeE(lr, lq), probeF(lq, lr), z, 0, 0, 0);
#pragma unroll
  for (int r = 0; r < 4; ++r) {
    double ref = 0.0;
#pragma unroll
    for (int k = 0; k < 4; ++k) ref += probeE(rowm[r], k) * probeF(k, cc & 15);
    okl = okl && (d[r] == ref);
  }
  return __all(okl) != 0;
}

// ---------------------------------------------------------------------------
// PING-PONG 64x64x64 fp64 matmul: D = (Cin ? Cin : 0) + A*B, no internal
// barriers. TWO independent accumulator chains (kb 0-7 / 8-15) halve the
// f64-MFMA dependency depth -- the measured limiter (51%/CU MfmaUtil with a
// single 16-deep chain). Result differs only in fp64 rounding association.
// ---------------------------------------------------------------------------
__device__ __forceinline__ void mmPP_mfma(const double* A, const double* B,
                                          const double* Cin, double* D,
                                          int wi, int wj, int lr, int lq,
                                          const int rowm[4], int colm)
{
  f64x4 a0, a1;
  if (Cin) {
#pragma unroll
    for (int r = 0; r < 4; ++r)
      a0[r] = Cin[(wi * 16 + rowm[r]) * 65 + wj * 16 + colm];
  } else {
    a0[0] = 0.0; a0[1] = 0.0; a0[2] = 0.0; a0[3] = 0.0;
  }
  a1[0] = 0.0; a1[1] = 0.0; a1[2] = 0.0; a1[3] = 0.0;
#pragma unroll
  for (int kb = 0; kb < 8; ++kb) {
    double a = A[(wi * 16 + lr) * 65 + kb * 4 + lq];
    double b = B[(kb * 4 + lq) * 65 + wj * 16 + lr];
    a0 = __builtin_amdgcn_mfma_f64_16x16x4f64(a, b, a0, 0, 0, 0);
    double a2 = A[(wi * 16 + lr) * 65 + (kb + 8) * 4 + lq];
    double b2 = B[((kb + 8) * 4 + lq) * 65 + wj * 16 + lr];
    a1 = __builtin_amdgcn_mfma_f64_16x16x4f64(a2, b2, a1, 0, 0, 0);
  }
#pragma unroll
  for (int r = 0; r < 4; ++r)
    D[(wi * 16 + rowm[r]) * 65 + wj * 16 + colm] = a0[r] + a1[r];
}

// VALU fallback, same buffer contract (2x2 tiles, 1024 threads).
__device__ __forceinline__ void mmPP_valu(const double* A, const double* B,
                                          const double* Cin, double* D,
                                          int tr2, int tc2)
{
  double a00, a01, a10, a11;
  if (Cin) {
    a00 = Cin[(tr2 + 0) * 65 + tc2 + 0]; a01 = Cin[(tr2 + 0) * 65 + tc2 + 1];
    a10 = Cin[(tr2 + 1) * 65 + tc2 + 0]; a11 = Cin[(tr2 + 1) * 65 + tc2 + 1];
  } else { a00 = a01 = a10 = a11 = 0.0; }
#pragma unroll 8
  for (int c = 0; c < 64; ++c) {
    double av0 = A[(tr2 + 0) * 65 + c];
    double av1 = A[(tr2 + 1) * 65 + c];
    double bv0 = B[c * 65 + tc2 + 0];
    double bv1 = B[c * 65 + tc2 + 1];
    a00 = fma(av0, bv0, a00); a01 = fma(av0, bv1, a01);
    a10 = fma(av1, bv0, a10); a11 = fma(av1, bv1, a11);
  }
  D[(tr2 + 0) * 65 + tc2 + 0] = a00;
  D[(tr2 + 0) * 65 + tc2 + 1] = a01;
  D[(tr2 + 1) * 65 + tc2 + 0] = a10;
  D[(tr2 + 1) * 65 + tc2 + 1] = a11;
}

// One 16x16 tile of the W/H log-doubling expansion (MFMA, probed maps,
// 2-chain). Writes rows [n,2n) -- disjoint from stage reads; no barrier.
__device__ __forceinline__ void wh_tile(const float* Wf, const float* Hf,
                                        const double* Pd, float* Wo, float* Ho,
                                        int n, bool isW, int wi, int wj,
                                        int lr, int lq, const int rowm[4], int colm)
{
  f64x4 a0, a1;
  a0[0] = 0.0; a0[1] = 0.0; a0[2] = 0.0; a0[3] = 0.0;
  a1[0] = 0.0; a1[1] = 0.0; a1[2] = 0.0; a1[3] = 0.0;
#pragma unroll
  for (int kb = 0; kb < 8; ++kb) {
    double a, b, a2, b2;
    if (isW) {
      a  = (double)Wf[(wi * 16 + lr) * 65 + kb * 4 + lq];
      b  = Pd[(wj * 16 + lr) * 65 + kb * 4 + lq];
      a2 = (double)Wf[(wi * 16 + lr) * 65 + (kb + 8) * 4 + lq];
      b2 = Pd[(wj * 16 + lr) * 65 + (kb + 8) * 4 + lq];
    } else {
      a  = (double)Hf[(wi * 16 + lr) * 65 + kb * 4 + lq];
      b  = Pd[(kb * 4 + lq) * 65 + wj * 16 + lr];
      a2 = (double)Hf[(wi * 16 + lr) * 65 + (kb + 8) * 4 + lq];
      b2 = Pd[((kb + 8) * 4 + lq) * 65 + wj * 16 + lr];
    }
    a0 = __builtin_amdgcn_mfma_f64_16x16x4f64(a,  b,  a0, 0, 0, 0);
    a1 = __builtin_amdgcn_mfma_f64_16x16x4f64(a2, b2, a1, 0, 0, 0);
  }
#pragma unroll
  for (int r = 0; r < 4; ++r) {
    int drow = wi * 16 + rowm[r];
    if (drow < n) {
      float v = (float)(a0[r] + a1[r]);
      if (isW) Wo[(n + drow) * 65 + wj * 16 + colm] = v;
      else     Ho[(n + drow) * 65 + wj * 16 + colm] = v;
    }
  }
}

// ---------------------------------------------------------------------------
// Kernel A: discretize + build all weights. 1 block x 1024 threads (16 waves).
// Ping-pong buffer flow, one barrier per stage, 2-chain MFMA accumulators.
// ---------------------------------------------------------------------------
__global__ __launch_bounds__(1024) void k_precomp(
    const float* __restrict__ Ain, const float* __restrict__ Bin,
    const float* __restrict__ Cin, const float* __restrict__ Din,
    const float* __restrict__ LS, float* ws)
{
  __shared__ double SB0[64 * 65];
  __shared__ double SB1[64 * 65];
  __shared__ double SB2[64 * 65];
  __shared__ double SB3[64 * 65];
  __shared__ float  Kf[128];
  float* Wf = (float*)SB0;   // 128x65 fp32 == 64x65 fp64 bytes
  float* Hf = (float*)SB1;

  const int t    = threadIdx.x;
  const int wave = t >> 6;
  const int lane = t & 63;
  const int lr   = lane & 15;
  const int lq   = lane >> 4;
  const int wv_i = wave >> 2;
  const int wv_j = wave & 3;
  const int tr2  = (t >> 5) << 1;
  const int tc2  = (t & 31) << 1;

  int rowm[4]; int colm;
  const bool use_mfma = probe_mfma_layout(lr, lq, rowm, &colm);

  unsigned short* Wtg = (unsigned short*)(ws + WS_W);
  unsigned short* Gtg = (unsigned short*)(ws + WS_G);
  float* Mf = ws + WS_MD;

  const double step = exp((double)LS[0]);
  const double h = 0.5 * step;

  // X = h*A -> SB0 ; Z = I + X -> SB2
  for (int idx = t; idx < 4096; idx += 1024) {
    int i = idx >> 6, j = idx & 63;
    double a = h * (double)Ain[idx];
    SB0[i * 65 + j] = a;
    SB2[i * 65 + j] = a + ((i == j) ? 1.0 : 0.0);
  }
  __syncthreads();

  // Product-form Neumann: Z <- Z + Z*X^2, X <- X^2, k=0..2
  // => Z = sum_{j=0}^{15} X^j ; truncation ||X||^16 <= 1e-16.
  {
    double *Xc = SB0, *Xn = SB1, *Zc = SB2, *Zn = SB3;
    for (int k = 0; k < 3; ++k) {
      if (use_mfma) mmPP_mfma(Xc, Xc, nullptr, Xn, wv_i, wv_j, lr, lq, rowm, colm);
      else          mmPP_valu(Xc, Xc, nullptr, Xn, tr2, tc2);
      __syncthreads();
      if (use_mfma) mmPP_mfma(Zc, Xn, Zc, Zn, wv_i, wv_j, lr, lq, rowm, colm);
      else          mmPP_valu(Zc, Xn, Zc, Zn, tr2, tc2);
      __syncthreads();
      double* tp_;
      tp_ = Xc; Xc = Xn; Xn = tp_;
      tp_ = Zc; Zc = Zn; Zn = tp_;
    }
    // N1 ends in SB3. X buffers dead.
  }

  // Bb = step * N1 @ B -> W[0] (Wf = dead SB0); Ab = 2*N1 - I -> SB2.
  if (t < 64) {
    double bb = 0.0;
    for (int c = 0; c < 64; ++c) bb = fma(SB3[t * 65 + c], (double)Bin[c], bb);
    Wf[t] = (float)(bb * step);
  }
  for (int idx = t; idx < 4096; idx += 1024) {
    int i = idx >> 6, j = idx & 63;
    SB2[i * 65 + j] = 2.0 * SB3[i * 65 + j] - ((i == j) ? 1.0 : 0.0);
  }
  __syncthreads();

  // H[0] = C @ Ab (reads SB2 cols; Hf = dead SB1)
  if (t < 64) {
    double hh = 0.0;
    for (int c = 0; c < 64; ++c) hh = fma((double)Cin[c], SB2[c * 65 + t], hh);
    Hf[t] = (float)hh;
  }
  __syncthreads();

  // Log-doubling: P = Ab^n (n = 2^k) ping-pongs SB2<->SB3. One barrier/stage.
  double* Pc = SB2;
  double* Pn = SB3;
  for (int k = 0; k < 7; ++k) {
    const int n = 1 << k;
    if (use_mfma) {
      const int tpm   = (n + 15) >> 4;
      const int tiles = tpm << 2;
      if (tiles <= 8) {
        if (wave < 2 * tiles) {
          const bool isW = wave < tiles;
          const int  wq  = isW ? wave : wave - tiles;
          wh_tile(Wf, Hf, Pc, Wf, Hf, n, isW, wq >> 2, wq & 3, lr, lq, rowm, colm);
        }
      } else {
        wh_tile(Wf, Hf, Pc, Wf, Hf, n, true,  wv_i, wv_j, lr, lq, rowm, colm);
        wh_tile(Wf, Hf, Pc, Wf, Hf, n, false, wv_i, wv_j, lr, lq, rowm, colm);
      }
      mmPP_mfma(Pc, Pc, nullptr, Pn, wv_i, wv_j, lr, lq, rowm, colm);
    } else {
      for (int o = t; o < (n << 6); o += 1024) {
        int r = o >> 6, ii = o & 63;
        double aw = 0.0, ah = 0.0;
#pragma unroll 4
        for (int c = 0; c < 64; ++c) {
          aw = fma(Pc[ii * 65 + c], (double)Wf[r * 65 + c], aw);
          ah = fma((double)Hf[r * 65 + c], Pc[c * 65 + ii], ah);
        }
        Wf[(n + r) * 65 + ii] = (float)aw;
        Hf[(n + r) * 65 + ii] = (float)ah;
      }
      mmPP_valu(Pc, Pc, nullptr, Pn, tr2, tc2);
    }
    __syncthreads();
    double* tp_ = Pc; Pc = Pn; Pn = tp_;
  }
  // Pc = Ab^128 = M.

  // Export M (float4-chunked layout for coalesced per-lane row reads).
  for (int idx = t; idx < 4096; idx += 1024) {
    int row = idx >> 6, col = idx & 63;
    Mf[((col >> 2) << 8) + (row << 2) + (col & 3)] = (float)Pc[row * 65 + col];
  }
  // M^2 -> Pn (export reads Pc; mm writes Pn -> no barrier needed between).
  if (use_mfma) mmPP_mfma(Pc, Pc, nullptr, Pn, wv_i, wv_j, lr, lq, rowm, colm);
  else          mmPP_valu(Pc, Pc, nullptr, Pn, tr2, tc2);
  __syncthreads();
  for (int idx = t; idx < 4096; idx += 1024) {
    int row = idx >> 6, col = idx & 63;
    Mf[4096 + ((col >> 2) << 8) + (row << 2) + (col & 3)] = (float)Pn[row * 65 + col];
  }

  // K[r] = C . W[r]
  if (t < 128) {
    double s = 0.0;
    for (int c = 0; c < 64; ++c) s = fma((double)Cin[c], (double)Wf[t * 65 + c], s);
    Kf[t] = (float)s;
  }
  __syncthreads();

  // Wt[i][k] = bf16(W[127-k][i])  (64 x 128)
  for (int idx = t; idx < 8192; idx += 1024) {
    int i = idx >> 7, kk = idx & 127;
    Wtg[idx] = f2bf(Wf[(127 - kk) * 65 + i]);
  }
  // Gt[r][k] bf16, stride 192. Toeplitz part (k<128): K[r-k] + D*(k==r).
  const float Dval = Din[0];
  for (int idx = t; idx < 16384; idx += 1024) {
    int r = idx >> 7, kg = idx & 127;
    float v = (r >= kg) ? Kf[r - kg] : 0.f;
    if (kg == r) v += Dval;
    Gtg[r * 192 + kg] = f2bf(v);
  }
  // Cross-chunk part: Gt[r][128+i] = bf16(H[r][i]).
  for (int idx = t; idx < 8192; idx += 1024) {
    int r = idx >> 6, i = idx & 63;
    Gtg[r * 192 + 128 + i] = f2bf(Hf[r * 65 + i]);
  }
}

// ---------------------------------------------------------------------------
// Kernel B': FUSED per-row pipeline with register-prefetch (T14) everywhere:
//   - Wt/u0/Mr loads issued together at kernel top
//   - u slices loaded into VGPRs BEFORE each MFMA cluster, written after
//   - Gs prefetched into regs by waves 1-3 DURING the serial scan (they
//     were idle ~25K cyc), written to LDS once the bs region dies
// Zero numerics changes vs round 8.
// ---------------------------------------------------------------------------
__global__ __launch_bounds__(256, 2) void k_fused(
    const float* __restrict__ u, const unsigned short* __restrict__ Wt,
    const unsigned short* __restrict__ Gt, const float* __restrict__ Mf,
    float* __restrict__ out)
{
  __shared__ __align__(16) unsigned char Lds[78848];
  float*          bs  = (float*)(Lds);                    // [128][68] ph1-2
  unsigned short* WtS = (unsigned short*)(Lds + 34816);   // [64][136] ph1
  float*          dsb = (float*)(Lds + 34816);            // [64][68]  ph2
  unsigned short* Gs  = (unsigned short*)(Lds);           // [128][200] ph3
  unsigned short* As  = (unsigned short*)(Lds + 52224);   // [128][40] ph1,3
  float*          xs  = (float*)(Lds + 62464);            // [64][64]  ph2
  unsigned short* Xbf = (unsigned short*)(Lds + 62464);   // [128][64] ph2-3

  const int t    = threadIdx.x;
  const int w    = t >> 6;
  const int lane = t & 63;
  const int lr   = lane & 15, lq = lane >> 4;
  const int row  = blockIdx.x;
  const float* urow = u + ((size_t)row << 14);   // 128 chunks x 128
  float* orow = out + ((size_t)row << 14);

  // ---- top: issue all initial global loads into registers ----
  unsigned wtv[16];
#pragma unroll
  for (int j = 0; j < 16; ++j) wtv[j] = ((const unsigned*)Wt)[t + j * 256];
  float4 uv[4];
#pragma unroll
  for (int j = 0; j < 4; ++j) {
    int it = t + j * 256;
    int rcl = it >> 3, k4 = (it & 7) << 2;
    uv[j] = *(const float4*)&urow[(rcl << 7) + k4];
  }
  float Mr[64];
#pragma unroll
  for (int c4 = 0; c4 < 16; ++c4)
    *(float4*)&Mr[c4 * 4] = *(const float4*)&Mf[(c4 << 8) + (lane << 2)];

  // write staged Wt + u slice 0
  {
    unsigned* dstW = (unsigned*)WtS;
#pragma unroll
    for (int j = 0; j < 16; ++j) {
      int idx = t + j * 256;
      dstW[(idx >> 6) * 68 + (idx & 63)] = wtv[j];
    }
  }
#pragma unroll
  for (int j = 0; j < 4; ++j) {
    int it = t + j * 256;
    int rcl = it >> 3, k4 = (it & 7) << 2;
    ushort4 s;
    s.x = f2bf(uv[j].x); s.y = f2bf(uv[j].y); s.z = f2bf(uv[j].z); s.w = f2bf(uv[j].w);
    *(ushort4*)&As[rcl * 40 + k4] = s;
  }
  __syncthreads();

  // ---- phase 1: chunk GEMM -> bs (LDS) ----
  {
    f32x4 acc[2][4];
#pragma unroll
    for (int i = 0; i < 2; ++i)
#pragma unroll
      for (int j = 0; j < 4; ++j) { acc[i][j][0] = 0.f; acc[i][j][1] = 0.f; acc[i][j][2] = 0.f; acc[i][j][3] = 0.f; }

    for (int sl = 0; sl < 4; ++sl) {
      float4 nv[4];
      if (sl < 3) {                      // prefetch next slice (latency under MFMA)
#pragma unroll
        for (int j = 0; j < 4; ++j) {
          int it = t + j * 256;
          int rcl = it >> 3, k4 = (it & 7) << 2;
          nv[j] = *(const float4*)&urow[(rcl << 7) + ((sl + 1) << 5) + k4];
        }
      }
      bf16x8 av[2], bv[4];
#pragma unroll
      for (int ti = 0; ti < 2; ++ti)
        av[ti] = *(const bf16x8*)&As[(w * 32 + ti * 16 + lr) * 40 + lq * 8];
#pragma unroll
      for (int tj = 0; tj < 4; ++tj)
        bv[tj] = *(const bf16x8*)&WtS[(tj * 16 + lr) * 136 + sl * 32 + lq * 8];
#pragma unroll
      for (int ti = 0; ti < 2; ++ti)
#pragma unroll
        for (int tj = 0; tj < 4; ++tj)
          acc[ti][tj] = __builtin_amdgcn_mfma_f32_16x16x32_bf16(av[ti], bv[tj], acc[ti][tj], 0, 0, 0);
      if (sl < 3) {
        __syncthreads();
#pragma unroll
        for (int j = 0; j < 4; ++j) {
          int it = t + j * 256;
          int rcl = it >> 3, k4 = (it & 7) << 2;
          ushort4 s;
          s.x = f2bf(nv[j].x); s.y = f2bf(nv[j].y); s.z = f2bf(nv[j].z); s.w = f2bf(nv[j].w);
          *(ushort4*)&As[rcl * 40 + k4] = s;
        }
        __syncthreads();
      }
    }
#pragma unroll
    for (int ti = 0; ti < 2; ++ti)
#pragma unroll
      for (int tj = 0; tj < 4; ++tj)
#pragma unroll
        for (int r = 0; r < 4; ++r)
          bs[(w * 32 + ti * 16 + lq * 4 + r) * 68 + tj * 16 + lr] = acc[ti][tj][r];
    __syncthreads();
  }

  // ---- phase 2: depth-halved scan ----
  {
    // Issue phase-3's first u slice early (write after d-phase; As is dead).
    float4 p3v[4];
#pragma unroll
    for (int j = 0; j < 4; ++j) {
      int it = t + j * 256;
      int rcl = it >> 3, k4 = (it & 7) << 2;
      p3v[j] = *(const float4*)&urow[(rcl << 7) + k4];
    }

    // d-phase: d_t = M b_{2t} + b_{2t+1}
    for (int k = 0; k < 16; ++k) {
      const int tp = (w << 4) + k;
      float y0 = 0.f, y1 = 0.f, y2 = 0.f, y3 = 0.f;
#pragma unroll
      for (int c4 = 0; c4 < 16; ++c4) {
        float4 bb = *(const float4*)&bs[(tp << 1) * 68 + (c4 << 2)];  // broadcast
        y0 = fmaf(Mr[c4 * 4 + 0], bb.x, y0);
        y1 = fmaf(Mr[c4 * 4 + 1], bb.y, y1);
        y2 = fmaf(Mr[c4 * 4 + 2], bb.z, y2);
        y3 = fmaf(Mr[c4 * 4 + 3], bb.w, y3);
      }
      dsb[tp * 68 + lane] = ((y0 + y1) + (y2 + y3)) + bs[((tp << 1) + 1) * 68 + lane];
    }
    // write pre-staged phase-3 slice 0 (As dead for reads since phase 1 end)
#pragma unroll
    for (int j = 0; j < 4; ++j) {
      int it = t + j * 256;
      int rcl = it >> 3, k4 = (it & 7) << 2;
      ushort4 s;
      s.x = f2bf(p3v[j].x); s.y = f2bf(p3v[j].y); s.z = f2bf(p3v[j].z); s.w = f2bf(p3v[j].w);
      *(ushort4*)&As[rcl * 40 + k4] = s;
    }
    __syncthreads();

    // Gs prefetch into regs by waves 1-3 (issued before the scan so the
    // ~25K-cyc serial region covers the global latency). 192 threads x 64.
    unsigned gv[64];
    if (w > 0) {
      const int t192 = t - 64;
#pragma unroll
      for (int j = 0; j < 64; ++j)
        gv[j] = ((const unsigned*)Gt)[j * 192 + t192];
    }

    // serial phase (wave 0): X_{2t+2} = M^2 X_{2t} + d_t, x in regs
    if (w == 0) {
      float M2r[64];
#pragma unroll
      for (int c4 = 0; c4 < 16; ++c4)
        *(float4*)&M2r[c4 * 4] = *(const float4*)&Mf[4096 + (c4 << 8) + (lane << 2)];
      float x = 0.f;
      float ecur = dsb[lane];
      for (int u2 = 0; u2 < 64; ++u2) {
        xs[(u2 << 6) + lane] = x;                     // X_{2u}
        float en = (u2 < 63) ? dsb[(u2 + 1) * 68 + lane] : 0.f;
        const unsigned xb = __float_as_uint(x);
        float y0 = 0.f, y1 = 0.f, y2 = 0.f, y3 = 0.f;
#pragma unroll
        for (int c = 0; c < 64; c += 4) {
          y0 = fmaf(M2r[c + 0], __uint_as_float(__builtin_amdgcn_readlane(xb, c + 0)), y0);
          y1 = fmaf(M2r[c + 1], __uint_as_float(__builtin_amdgcn_readlane(xb, c + 1)), y1);
          y2 = fmaf(M2r[c + 2], __uint_as_float(__builtin_amdgcn_readlane(xb, c + 2)), y2);
          y3 = fmaf(M2r[c + 3], __uint_as_float(__builtin_amdgcn_readlane(xb, c + 3)), y3);
        }
        x = ((y0 + y1) + (y2 + y3)) + ecur;
        ecur = en;
      }
    }
    __syncthreads();

    // fixup: Xbf[2t] = bf16(xs[t]); Xbf[2t+1] = bf16(M xs[t] + b_{2t}).
    for (int k = 0; k < 16; ++k) {
      const int tp = (w << 4) + k;
      float y0 = 0.f, y1 = 0.f, y2 = 0.f, y3 = 0.f;
#pragma unroll
      for (int c4 = 0; c4 < 16; ++c4) {
        float4 xx = *(const float4*)&xs[(tp << 6) + (c4 << 2)];  // broadcast
        y0 = fmaf(Mr[c4 * 4 + 0], xx.x, y0);
        y1 = fmaf(Mr[c4 * 4 + 1], xx.y, y1);
        y2 = fmaf(Mr[c4 * 4 + 2], xx.z, y2);
        y3 = fmaf(Mr[c4 * 4 + 3], xx.w, y3);
      }
      float xeven = xs[(tp << 6) + lane];                 // read before alias-write
      float xodd  = ((y0 + y1) + (y2 + y3)) + bs[(tp << 1) * 68 + lane];
      Xbf[((tp << 1) + 0) * 64 + lane] = f2bf(xeven);
      Xbf[((tp << 1) + 1) * 64 + lane] = f2bf(xodd);
    }
    __syncthreads();

    // Gs regs -> LDS (bs/dsb region now dead).
    if (w > 0) {
      const int t192 = t - 64;
      const int hi = (t192 >= 96) ? 1 : 0;
      const int lo = t192 - 96 * hi;
      unsigned* dstG = (unsigned*)Gs;
#pragma unroll
      for (int j = 0; j < 64; ++j)
        dstG[(2 * j + hi) * 100 + lo] = gv[j];
    }
    __syncthreads();
  }

  // ---- phase 3: main GEMM -> out ----
  {
    f32x4 acc[2][8];
#pragma unroll
    for (int i = 0; i < 2; ++i)
#pragma unroll
      for (int j = 0; j < 8; ++j) { acc[i][j][0] = 0.f; acc[i][j][1] = 0.f; acc[i][j][2] = 0.f; acc[i][j][3] = 0.f; }

    for (int sl = 0; sl < 6; ++sl) {
      float4 nv[4];
      if (sl < 3) {                      // prefetch u slice sl+1
#pragma unroll
        for (int j = 0; j < 4; ++j) {
          int it = t + j * 256;
          int rcl = it >> 3, k4 = (it & 7) << 2;
          nv[j] = *(const float4*)&urow[(rcl << 7) + ((sl + 1) << 5) + k4];
        }
      }
      bf16x8 av[2], bv[8];
#pragma unroll
      for (int ti = 0; ti < 2; ++ti) {
        if (sl < 4)
          av[ti] = *(const bf16x8*)&As[(w * 32 + ti * 16 + lr) * 40 + lq * 8];
        else
          av[ti] = *(const bf16x8*)&Xbf[(w * 32 + ti * 16 + lr) * 64 + (sl - 4) * 32 + lq * 8];
      }
#pragma unroll
      for (int tj = 0; tj < 8; ++tj)
        bv[tj] = *(const bf16x8*)&Gs[(tj * 16 + lr) * 200 + sl * 32 + lq * 8];
#pragma unroll
      for (int ti = 0; ti < 2; ++ti)
#pragma unroll
        for (int tj = 0; tj < 8; ++tj)
          acc[ti][tj] = __builtin_amdgcn_mfma_f32_16x16x32_bf16(av[ti], bv[tj], acc[ti][tj], 0, 0, 0);
      if (sl < 3) {
        __syncthreads();
#pragma unroll
        for (int j = 0; j < 4; ++j) {
          int it = t + j * 256;
          int rcl = it >> 3, k4 = (it & 7) << 2;
          ushort4 s;
          s.x = f2bf(nv[j].x); s.y = f2bf(nv[j].y); s.z = f2bf(nv[j].z); s.w = f2bf(nv[j].w);
          *(ushort4*)&As[rcl * 40 + k4] = s;
        }
        __syncthreads();
      }
    }

#pragma unroll
    for (int ti = 0; ti < 2; ++ti)
#pragma unroll
      for (int tj = 0; tj < 8; ++tj)
#pragma unroll
        for (int r = 0; r < 4; ++r) {
          int rcl = w * 32 + ti * 16 + lq * 4 + r;
          orow[((size_t)rcl << 7) + tj * 16 + lr] = acc[ti][tj][r];
        }
  }
}

// ---------------------------------------------------------------------------
extern "C" void kernel_launch(void* const* d_in, const int* in_sizes, int n_in,
                              void* d_out, int out_size, void* d_ws, size_t ws_size,
                              hipStream_t stream) {
  (void)in_sizes; (void)n_in; (void)out_size; (void)ws_size;
  const float* u  = (const float*)d_in[0];
  const float* A  = (const float*)d_in[1];
  const float* Bv = (const float*)d_in[2];
  const float* Cv = (const float*)d_in[3];
  const float* Dv = (const float*)d_in[4];
  const float* ls = (const float*)d_in[5];
  float* out = (float*)d_out;
  float* ws  = (float*)d_ws;

  k_precomp<<<1, 1024, 0, stream>>>(A, Bv, Cv, Dv, ls, ws);
  k_fused<<<512, 256, 0, stream>>>(u, (const unsigned short*)(ws + WS_W),
                                   (const unsigned short*)(ws + WS_G),
                                   ws + WS_MD, out);
}